// Round 7
// baseline (339.543 us; speedup 1.0000x reference)
//
#include <hip/hip_runtime.h>
#include <math.h>

#define BB 8
#define CC 512
#define SS 1024
#define NHH 8
#define HDD 64
#define KD 512

typedef __attribute__((ext_vector_type(8))) short short8;
typedef __attribute__((ext_vector_type(4))) float f32x4;
typedef __attribute__((ext_vector_type(4))) unsigned short ushort4v;

__device__ __forceinline__ unsigned short f2bf(float x) {
  union { float f; unsigned int u; } c; c.f = x;
  unsigned int r = (c.u + 0x7FFFu + ((c.u >> 16) & 1u)) >> 16;
  return (unsigned short)r;
}
__device__ __forceinline__ float b2f(unsigned short h) {
  union { unsigned int u; float f; } c; c.u = ((unsigned int)h) << 16; return c.f;
}

#define GLD_LDS(gp, lp) __builtin_amdgcn_global_load_lds( \
    (const __attribute__((address_space(1))) void*)(gp),  \
    (__attribute__((address_space(3))) void*)(lp), 16, 0, 0)

// ---------- block-wide sum over 256 threads (4 waves) ----------
__device__ __forceinline__ float block_reduce_sum(float v) {
  __shared__ float sm[4];
  #pragma unroll
  for (int o = 32; o > 0; o >>= 1) v += __shfl_down(v, o, 64);
  if ((threadIdx.x & 63) == 0) sm[threadIdx.x >> 6] = v;
  __syncthreads();
  float r = (sm[0] + sm[1]) + (sm[2] + sm[3]);
  __syncthreads();
  return r;
}

// ---------- fused transpose + LayerNorm1: x (B,C,S) -> ln1 h/l + xs h/l ------
// block (32,8): handles (b, 32 s-rows); two passes over C (2nd pass L2-hot)
__global__ __launch_bounds__(256) void ln1_fused(
    const float* __restrict__ x, const float* __restrict__ g,
    const float* __restrict__ be,
    unsigned short* __restrict__ yh, unsigned short* __restrict__ yl,
    unsigned short* __restrict__ xh, unsigned short* __restrict__ xl) {
  __shared__ float tile[32][33];
  __shared__ float red[2][8][33];
  __shared__ float mu_s[32], rs_s[32];
  const int b = blockIdx.y, s0 = blockIdx.x * 32;
  const int tx = threadIdx.x, ty = threadIdx.y;
  const float* xb = x + (size_t)b * CC * SS;
  float psum = 0.f, psq = 0.f;
  for (int c0 = 0; c0 < CC; c0 += 32) {
    __syncthreads();
    #pragma unroll
    for (int i = ty; i < 32; i += 8)
      tile[i][tx] = xb[(size_t)(c0 + i) * SS + s0 + tx];
    __syncthreads();
    #pragma unroll
    for (int k = 0; k < 4; ++k) {
      const float v = tile[ty * 4 + k][tx];
      psum += v; psq += v * v;
    }
  }
  red[0][ty][tx] = psum; red[1][ty][tx] = psq;
  __syncthreads();
  if (ty == 0) {
    float s = 0.f, q = 0.f;
    #pragma unroll
    for (int k = 0; k < 8; ++k) { s += red[0][k][tx]; q += red[1][k][tx]; }
    const float mu = s * (1.0f / CC);
    mu_s[tx] = mu;
    rs_s[tx] = rsqrtf(q * (1.0f / CC) - mu * mu + 1e-5f);
  }
  __syncthreads();
  for (int c0 = 0; c0 < CC; c0 += 32) {
    __syncthreads();
    #pragma unroll
    for (int i = ty; i < 32; i += 8)
      tile[i][tx] = xb[(size_t)(c0 + i) * SS + s0 + tx];
    __syncthreads();
    const float gc = g[c0 + tx], bc = be[c0 + tx];
    #pragma unroll
    for (int i = ty; i < 32; i += 8) {
      const float v = tile[tx][i];  // c = c0+tx, s = s0+i
      const float y = (v - mu_s[i]) * rs_s[i] * gc + bc;
      const size_t oi = ((size_t)b * SS + s0 + i) * CC + c0 + tx;
      const unsigned short hy = f2bf(y);
      yh[oi] = hy; yl[oi] = f2bf(y - b2f(hy));
      const unsigned short hx = f2bf(v);
      xh[oi] = hx; xl[oi] = f2bf(v - b2f(hx));
    }
  }
}

// ---------- LayerNorm (C=512) contiguous rows -> bf16 hi ---------------------
__global__ __launch_bounds__(256) void ln_bf16_k(const float* __restrict__ in,
                                                 const float* __restrict__ g,
                                                 const float* __restrict__ be,
                                                 unsigned short* __restrict__ outh) {
  size_t row = blockIdx.x;
  const float* r = in + row * CC;
  int t = threadIdx.x;
  float v0 = r[t], v1 = r[t + 256];
  float s = block_reduce_sum(v0 + v1);
  float mu = s * (1.0f / CC);
  float d0 = v0 - mu, d1 = v1 - mu;
  float vs = block_reduce_sum(d0 * d0 + d1 * d1);
  float rstd = rsqrtf(vs * (1.0f / CC) + 1e-5f);
  outh[row * CC + t]       = f2bf(d0 * rstd * g[t] + be[t]);
  outh[row * CC + t + 256] = f2bf(d1 * rstd * g[t + 256] + be[t + 256]);
}

// ---------- weight convert: fp32 -> bf16 hi/lo B^T (N,K) ---------------------
__global__ __launch_bounds__(256) void convert_weights(
    const float* __restrict__ QW, const float* __restrict__ KW,
    const float* __restrict__ VW, const float* __restrict__ OW,
    const float* __restrict__ W1, const float* __restrict__ W2,
    const float* __restrict__ Qb, const float* __restrict__ Kb,
    const float* __restrict__ Vb,
    unsigned short* __restrict__ BtQKh, unsigned short* __restrict__ BtQKl,
    unsigned short* __restrict__ BtVh,
    unsigned short* __restrict__ BtOh, unsigned short* __restrict__ BtOl,
    unsigned short* __restrict__ BtW1h, unsigned short* __restrict__ BtW2h,
    float* __restrict__ qkvb) {
  __shared__ float tile[32][33];
  const int p = blockIdx.z, wsel = p >> 3, sub = p & 7;
  const int k0 = blockIdx.x * 32, d0 = blockIdx.y * 32;
  const int tx = threadIdx.x, ty = threadIdx.y;
  const float* w; int rs; unsigned short *dh, *dl; int nbase;
  switch (wsel) {
    case 0:  w = QW + sub * 32768; rs = 64;  dh = BtQKh; dl = BtQKl;  nbase = sub * 64;        break;
    case 1:  w = KW + sub * 32768; rs = 64;  dh = BtQKh; dl = BtQKl;  nbase = 512 + sub * 64;  break;
    case 2:  w = VW + sub * 32768; rs = 64;  dh = BtVh;  dl = nullptr; nbase = sub * 64;       break;
    case 3:  w = OW + sub * 64;    rs = 512; dh = BtOh;  dl = BtOl;   nbase = sub * 64;        break;
    case 4:  w = W1 + sub * 64;    rs = 512; dh = BtW1h; dl = nullptr; nbase = sub * 64;       break;
    default: w = W2 + sub * 64;    rs = 512; dh = BtW2h; dl = nullptr; nbase = sub * 64;       break;
  }
  for (int i = ty; i < 32; i += 8)
    tile[i][tx] = w[(size_t)(k0 + i) * rs + d0 + tx];
  __syncthreads();
  for (int i = ty; i < 32; i += 8) {
    float f = tile[tx][i];
    unsigned short h = f2bf(f);
    size_t idx = (size_t)(nbase + d0 + i) * KD + k0 + tx;
    dh[idx] = h;
    if (dl) dl[idx] = f2bf(f - b2f(h));
  }
  if (p == 0 && blockIdx.x == 0 && blockIdx.y == 0) {
    int t = ty * 32 + tx;
    for (int i = t; i < 1536; i += 256)
      qkvb[i] = i < 512 ? Qb[i] : (i < 1024 ? Kb[i - 512] : Vb[i - 1024]);
  }
}

// ---------- fused QKV projection GEMM, 128x128 tiles, xor-swizzled LDS -------
// V output scattered to vt (B, NH, HD, S) bf16 for GLD-friendly attn staging.
__global__ __launch_bounds__(256) void gemm_qkv(
    const unsigned short* __restrict__ Ah, const unsigned short* __restrict__ Al,
    const unsigned short* __restrict__ Bth, const unsigned short* __restrict__ Btl,
    const float* __restrict__ bias,
    unsigned short* __restrict__ qkh, unsigned short* __restrict__ qkl,
    unsigned short* __restrict__ vt) {
  __shared__ __align__(16) unsigned short As[2 * 128 * 32];
  __shared__ __align__(16) unsigned short Bs[2 * 128 * 32];
  const int tid = threadIdx.x;
  const int w = tid >> 6, l = tid & 63, quad = l >> 4, lm = l & 15;
  const int n0 = blockIdx.x * 128, m0 = blockIdx.y * 128;
  const bool splitB = n0 < 1024;
  const int wm = (w >> 1) * 64, wn = (w & 1) * 64;
  const int srow = tid >> 2;
  const int sch = (((tid & 3) ^ (srow & 3)) * 8);
  const unsigned short* Agh = Ah + (size_t)(m0 + srow) * KD + sch;
  const unsigned short* Agl = Al + (size_t)(m0 + srow) * KD + sch;
  const unsigned short* Bgh = Bth + (size_t)(n0 + srow) * KD + sch;
  const unsigned short* Bgl = Btl + (size_t)(n0 + srow) * KD + sch;
  unsigned short* Aswh = As + w * 512;
  unsigned short* Aswl = As + 4096 + w * 512;
  unsigned short* Bswh = Bs + w * 512;
  unsigned short* Bswl = Bs + 4096 + w * 512;
  const int rch = ((quad ^ (lm & 3)) * 8);
  const f32x4 fzero = {0.f, 0.f, 0.f, 0.f};
  f32x4 acc[4][4];
  #pragma unroll
  for (int i = 0; i < 4; ++i)
    #pragma unroll
    for (int j = 0; j < 4; ++j) acc[i][j] = fzero;
  for (int k0 = 0; k0 < KD; k0 += 32) {
    __syncthreads();
    GLD_LDS(Agh + k0, Aswh);
    GLD_LDS(Agh + k0 + 64 * KD, Aswh + 2048);
    GLD_LDS(Agl + k0, Aswl);
    GLD_LDS(Agl + k0 + 64 * KD, Aswl + 2048);
    GLD_LDS(Bgh + k0, Bswh);
    GLD_LDS(Bgh + k0 + 64 * KD, Bswh + 2048);
    if (splitB) {
      GLD_LDS(Bgl + k0, Bswl);
      GLD_LDS(Bgl + k0 + 64 * KD, Bswl + 2048);
    }
    __syncthreads();
    short8 afh[4], afl[4], bfh[4], bfl[4];
    #pragma unroll
    for (int i = 0; i < 4; ++i) {
      afh[i] = *(const short8*)(As + (wm + i * 16 + lm) * 32 + rch);
      afl[i] = *(const short8*)(As + 4096 + (wm + i * 16 + lm) * 32 + rch);
    }
    #pragma unroll
    for (int j = 0; j < 4; ++j)
      bfh[j] = *(const short8*)(Bs + (wn + j * 16 + lm) * 32 + rch);
    if (splitB) {
      #pragma unroll
      for (int j = 0; j < 4; ++j)
        bfl[j] = *(const short8*)(Bs + 4096 + (wn + j * 16 + lm) * 32 + rch);
      #pragma unroll
      for (int i = 0; i < 4; ++i)
        #pragma unroll
        for (int j = 0; j < 4; ++j) {
          f32x4 t = acc[i][j];
          t = __builtin_amdgcn_mfma_f32_16x16x32_bf16(afh[i], bfh[j], t, 0, 0, 0);
          t = __builtin_amdgcn_mfma_f32_16x16x32_bf16(afh[i], bfl[j], t, 0, 0, 0);
          t = __builtin_amdgcn_mfma_f32_16x16x32_bf16(afl[i], bfh[j], t, 0, 0, 0);
          acc[i][j] = t;
        }
    } else {
      #pragma unroll
      for (int i = 0; i < 4; ++i)
        #pragma unroll
        for (int j = 0; j < 4; ++j)
          acc[i][j] = __builtin_amdgcn_mfma_f32_16x16x32_bf16(afh[i], bfh[j], acc[i][j], 0, 0, 0);
    }
  }
  #pragma unroll
  for (int i = 0; i < 4; ++i) {
    const int row = m0 + wm + i * 16 + quad * 4;
    #pragma unroll
    for (int j = 0; j < 4; ++j) {
      const int ncol = n0 + wn + j * 16 + lm;
      const float bv = bias[ncol];
      if (splitB) {
        #pragma unroll
        for (int r = 0; r < 4; ++r) {
          const float xv = acc[i][j][r] + bv;
          const size_t oi = (size_t)(row + r) * 1024 + ncol;
          unsigned short h = f2bf(xv);
          qkh[oi] = h;
          qkl[oi] = f2bf(xv - b2f(h));
        }
      } else {
        const int hd = ncol - 1024, hh = hd >> 6, dd = hd & 63;
        const int bb2 = row >> 10, s = row & 1023;
        ushort4v pack;
        #pragma unroll
        for (int r = 0; r < 4; ++r) pack[r] = f2bf(acc[i][j][r] + bv);
        *(ushort4v*)(vt + ((size_t)(bb2 * 8 + hh) * 64 + dd) * 1024 + s) = pack;
      }
    }
  }
}

// ---------- 64x64-tile GEMM, xor-swizzled --------------------------------
// RESID: 0 none, 1 fp32 ptr, 2 bf16 h+l pair. TRANS: write (B,C,S) via LDS.
template<int SB, int GELU, int OUTMODE, int RESID, int TRANS>
__global__ __launch_bounds__(256) void gemm64(
    const unsigned short* __restrict__ Ah,
    const unsigned short* __restrict__ Bh, const unsigned short* __restrict__ Bl,
    const float* __restrict__ bias, const float* __restrict__ residf,
    const unsigned short* __restrict__ residh, const unsigned short* __restrict__ residl,
    unsigned short* __restrict__ outh, float* __restrict__ outf, int ldc) {
  __shared__ __align__(16) unsigned short As[64 * 32];
  __shared__ __align__(16) unsigned short Bs[(SB ? 2 : 1) * 64 * 32];
  __shared__ float ttile[TRANS ? 64 : 1][TRANS ? 65 : 1];
  const int tid = threadIdx.x;
  const int w = tid >> 6, l = tid & 63, quad = l >> 4, lm = l & 15;
  const int n0 = blockIdx.x * 64, m0 = blockIdx.y * 64;
  const int wm = (w >> 1) * 32, wn = (w & 1) * 32;
  const int srow = tid >> 2;
  const int sch = (((tid & 3) ^ (srow & 3)) * 8);
  const unsigned short* Ag = Ah + (size_t)(m0 + srow) * KD + sch;
  const unsigned short* Bg = Bh + (size_t)(n0 + srow) * KD + sch;
  const unsigned short* Bgl = SB ? Bl + (size_t)(n0 + srow) * KD + sch : nullptr;
  unsigned short* Asw = As + w * 512;
  unsigned short* Bsw = Bs + w * 512;
  unsigned short* Bswl = Bs + 2048 + w * 512;
  const int rch = ((quad ^ (lm & 3)) * 8);
  const f32x4 fzero = {0.f, 0.f, 0.f, 0.f};
  f32x4 acc[2][2];
  #pragma unroll
  for (int i = 0; i < 2; ++i)
    #pragma unroll
    for (int j = 0; j < 2; ++j) acc[i][j] = fzero;
  for (int k0 = 0; k0 < KD; k0 += 32) {
    __syncthreads();
    GLD_LDS(Ag + k0, Asw);
    GLD_LDS(Bg + k0, Bsw);
    if constexpr (SB) GLD_LDS(Bgl + k0, Bswl);
    __syncthreads();
    short8 af[2], bfh[2], bfl[2];
    #pragma unroll
    for (int i = 0; i < 2; ++i)
      af[i] = *(const short8*)(As + (wm + i * 16 + lm) * 32 + rch);
    #pragma unroll
    for (int j = 0; j < 2; ++j)
      bfh[j] = *(const short8*)(Bs + (wn + j * 16 + lm) * 32 + rch);
    if constexpr (SB) {
      #pragma unroll
      for (int j = 0; j < 2; ++j)
        bfl[j] = *(const short8*)(Bs + 2048 + (wn + j * 16 + lm) * 32 + rch);
    }
    #pragma unroll
    for (int i = 0; i < 2; ++i)
      #pragma unroll
      for (int j = 0; j < 2; ++j) {
        f32x4 t = acc[i][j];
        t = __builtin_amdgcn_mfma_f32_16x16x32_bf16(af[i], bfh[j], t, 0, 0, 0);
        if constexpr (SB)
          t = __builtin_amdgcn_mfma_f32_16x16x32_bf16(af[i], bfl[j], t, 0, 0, 0);
        acc[i][j] = t;
      }
  }
  if constexpr (TRANS) __syncthreads();
  #pragma unroll
  for (int i = 0; i < 2; ++i) {
    const int row = m0 + wm + i * 16 + quad * 4;
    #pragma unroll
    for (int j = 0; j < 2; ++j) {
      const int col = n0 + wn + j * 16 + lm;
      const float bv = bias[col];
      #pragma unroll
      for (int r = 0; r < 4; ++r) {
        float x = acc[i][j][r] + bv;
        if (GELU) x = 0.5f * x * (1.0f + erff(x * 0.70710678118654752f));
        const size_t ri = (size_t)(row + r) * CC + col;
        if (RESID == 1) x += residf[ri];
        if (RESID == 2) x += b2f(residh[ri]) + b2f(residl[ri]);
        if constexpr (TRANS) {
          ttile[wm + i * 16 + quad * 4 + r][wn + j * 16 + lm] = x;
        } else {
          const size_t oi = (size_t)(row + r) * ldc + col;
          if (OUTMODE == 0) outf[oi] = x;
          else outh[oi] = f2bf(x);
        }
      }
    }
  }
  if constexpr (TRANS) {
    __syncthreads();
    const int bi = m0 >> 10, s0 = m0 & 1023;
    const int s = tid & 63;
    #pragma unroll
    for (int c0 = 0; c0 < 64; c0 += 4) {
      const int col = c0 + (tid >> 6);
      outf[(size_t)(bi * 512 + n0 + col) * 1024 + s0 + s] = ttile[s][col];
    }
  }
}

// ---------- flash attention: GLD_LDS K & V^T staging, exp2 softmax -----------
// QK hi/lo: (B, S, 1024) [Q | K]; Vt: (B, NH, HD, S); O: (B, S, 512) bf16
__global__ __launch_bounds__(256) void attn_mfma(
    const unsigned short* __restrict__ QKh, const unsigned short* __restrict__ QKl,
    const unsigned short* __restrict__ Vt, unsigned short* __restrict__ Oh) {
  __shared__ __align__(16) unsigned short Ksh[64 * 64], Ksl[64 * 64];
  __shared__ __align__(16) unsigned short Vts[64 * 64];
  __shared__ __align__(16) unsigned short Ps[4 * 16 * 88];
  const int q0 = blockIdx.x * 64, h = blockIdx.y, b = blockIdx.z;
  const int tid = threadIdx.x, w = tid >> 6, l = tid & 63, quad = l >> 4, lm = l & 15;
  const int LDQ = 2 * CC;
  const size_t qkbase = (size_t)b * SS * LDQ;
  const int srow8 = tid >> 3;                       // 0..31
  const int sch8  = ((tid & 7) ^ (srow8 & 7)) * 8;  // xor-swizzled chunk (shorts)
  const unsigned short* Vg = Vt + ((size_t)(b * 8 + h) * 64 + srow8) * 1024 + sch8;
  // Q fragments (A-layout: m=lm, k=st*32+quad*8)
  short8 qh[2], ql[2];
  {
    const size_t qo = qkbase + (size_t)(q0 + w * 16 + lm) * LDQ + h * 64 + quad * 8;
    qh[0] = *(const short8*)(QKh + qo);
    qh[1] = *(const short8*)(QKh + qo + 32);
    ql[0] = *(const short8*)(QKl + qo);
    ql[1] = *(const short8*)(QKl + qo + 32);
  }
  short8 bones;
  #pragma unroll
  for (int u = 0; u < 8; ++u) bones[u] = (lm == 0) ? (short)0x3F80 : (short)0;
  const f32x4 fzero = {0.f, 0.f, 0.f, 0.f};
  float mrow[4];
  f32x4 oacc[5];  // [0..3]=O cols, [4]=row-sum
  #pragma unroll
  for (int r = 0; r < 4; ++r) mrow[r] = -1e30f;
  #pragma unroll
  for (int j = 0; j < 5; ++j) oacc[j] = fzero;
  // scale * log2(e): softmax computed in exp2 domain (monotonic, same argmax)
  const float scale = 0.044194173824159216f * 1.4426950408889634f;
  unsigned short* Pw = Ps + w * (16 * 88);
  for (int kt = 0; kt < SS; kt += 64) {
    __syncthreads();
    {
      const unsigned short* kg  = QKh + qkbase + (size_t)(kt + srow8) * LDQ + CC + h * 64 + sch8;
      const unsigned short* kgl = QKl + qkbase + (size_t)(kt + srow8) * LDQ + CC + h * 64 + sch8;
      GLD_LDS(kg, Ksh + w * 512);
      GLD_LDS(kg + 32 * LDQ, Ksh + 2048 + w * 512);
      GLD_LDS(kgl, Ksl + w * 512);
      GLD_LDS(kgl + 32 * LDQ, Ksl + 2048 + w * 512);
      GLD_LDS(Vg + kt, Vts + w * 512);
      GLD_LDS(Vg + kt + 32 * 1024, Vts + 2048 + w * 512);
    }
    __syncthreads();
    f32x4 sc[4];
    #pragma unroll
    for (int j = 0; j < 4; ++j) sc[j] = fzero;
    #pragma unroll
    for (int st = 0; st < 2; ++st) {
      const int kc = ((st * 4 + quad) ^ (lm & 7)) * 8;
      #pragma unroll
      for (int j = 0; j < 4; ++j) {
        short8 kh = *(const short8*)(Ksh + (j * 16 + lm) * 64 + kc);
        short8 kl = *(const short8*)(Ksl + (j * 16 + lm) * 64 + kc);
        f32x4 t = sc[j];
        t = __builtin_amdgcn_mfma_f32_16x16x32_bf16(qh[st], kh, t, 0, 0, 0);
        t = __builtin_amdgcn_mfma_f32_16x16x32_bf16(qh[st], kl, t, 0, 0, 0);
        t = __builtin_amdgcn_mfma_f32_16x16x32_bf16(ql[st], kh, t, 0, 0, 0);
        sc[j] = t;
      }
    }
    #pragma unroll
    for (int j = 0; j < 4; ++j) sc[j] *= scale;
    #pragma unroll
    for (int r = 0; r < 4; ++r) {
      float mt = fmaxf(fmaxf(sc[0][r], sc[1][r]), fmaxf(sc[2][r], sc[3][r]));
      #pragma unroll
      for (int mask = 1; mask < 16; mask <<= 1) mt = fmaxf(mt, __shfl_xor(mt, mask, 64));
      const float mn = fmaxf(mrow[r], mt);
      const float alpha = exp2f(mrow[r] - mn);
      mrow[r] = mn;
      #pragma unroll
      for (int j = 0; j < 4; ++j) sc[j][r] = exp2f(sc[j][r] - mn);
      #pragma unroll
      for (int j = 0; j < 5; ++j) oacc[j][r] *= alpha;
    }
    #pragma unroll
    for (int r = 0; r < 4; ++r)
      #pragma unroll
      for (int j = 0; j < 4; ++j)
        Pw[(quad * 4 + r) * 88 + j * 16 + lm] = f2bf(sc[j][r]);
    #pragma unroll
    for (int st = 0; st < 2; ++st) {
      short8 ap = *(const short8*)(Pw + lm * 88 + st * 32 + quad * 8);
      const int kc = ((st * 4 + quad) ^ (lm & 7)) * 8;
      #pragma unroll
      for (int j = 0; j < 4; ++j) {
        short8 vv = *(const short8*)(Vts + (j * 16 + lm) * 64 + kc);
        oacc[j] = __builtin_amdgcn_mfma_f32_16x16x32_bf16(ap, vv, oacc[j], 0, 0, 0);
      }
      oacc[4] = __builtin_amdgcn_mfma_f32_16x16x32_bf16(ap, bones, oacc[4], 0, 0, 0);
    }
  }
  float inv[4];
  #pragma unroll
  for (int r = 0; r < 4; ++r) {
    const float lv = __shfl(oacc[4][r], l & 48, 64);
    inv[r] = 1.f / lv;
  }
  const size_t obase =
      (size_t)b * SS * CC + (size_t)(q0 + w * 16 + quad * 4) * CC + h * 64 + lm;
  #pragma unroll
  for (int j = 0; j < 4; ++j)
    #pragma unroll
    for (int r = 0; r < 4; ++r)
      Oh[obase + (size_t)r * CC + j * 16] = f2bf(oacc[j][r] * inv[r]);
}

extern "C" void kernel_launch(void* const* d_in, const int* in_sizes, int n_in,
                              void* d_out, int out_size, void* d_ws, size_t ws_size,
                              hipStream_t stream) {
  const float* x    = (const float*)d_in[0];
  const float* K_W  = (const float*)d_in[2];
  const float* K_b  = (const float*)d_in[3];
  const float* Q_W  = (const float*)d_in[4];
  const float* Q_b  = (const float*)d_in[5];
  const float* V_W  = (const float*)d_in[6];
  const float* V_b  = (const float*)d_in[7];
  const float* O_W  = (const float*)d_in[8];
  const float* O_b  = (const float*)d_in[9];
  const float* ln1g = (const float*)d_in[10];
  const float* ln1b = (const float*)d_in[11];
  const float* ln2g = (const float*)d_in[12];
  const float* ln2b = (const float*)d_in[13];
  const float* W1   = (const float*)d_in[14];
  const float* b1   = (const float*)d_in[15];
  const float* W2   = (const float*)d_in[16];
  const float* b2   = (const float*)d_in[17];
  float* out = (float*)d_out;

  unsigned char* ws = (unsigned char*)d_ws;
  const size_t MB = 1u << 20;
  unsigned short* qkh   = (unsigned short*)(ws);             // (B,S,1024) 16MB
  unsigned short* qkl   = (unsigned short*)(ws + 16 * MB);   // 16MB
  unsigned short* vt    = (unsigned short*)(ws + 32 * MB);   // (B,NH,HD,S) 8MB
  unsigned short* ln1h  = (unsigned short*)(ws + 40 * MB);   // 8MB
  unsigned short* ln1l  = (unsigned short*)(ws + 48 * MB);   // 8MB
  unsigned short* xsh   = (unsigned short*)(ws + 56 * MB);   // 8MB (residual hi)
  unsigned short* xsl   = (unsigned short*)(ws + 64 * MB);   // 8MB (residual lo)
  unsigned short* oh    = ln1h;                              // reuse after QKV GEMM
  float* out1           = (float*)(ws + 72 * MB);            // 16MB fp32 residual
  unsigned short* ln2h  = qkh;                               // reuse (qk dead post-attn)
  unsigned short* geluh = (unsigned short*)(ws + 8 * MB);    // reuse qkh 2nd half
  unsigned short* BtAll = (unsigned short*)(ws + 88 * MB);   // [QKh 1024 | Vh 512] x 512
  unsigned short* BtQKh = BtAll;
  unsigned short* BtVh  = BtAll + 1024 * 512;
  unsigned short* BtQKl = BtVh + 512 * 512;
  unsigned short* BtOh  = BtQKl + 1024 * 512;
  unsigned short* BtOl  = BtOh + 512 * 512;
  unsigned short* BtW1h = BtOl + 512 * 512;
  unsigned short* BtW2h = BtW1h + 512 * 512;
  float* qkvb           = (float*)(BtW2h + 512 * 512);

  dim3 tb32(32, 8);
  convert_weights<<<dim3(16, 2, 48), tb32, 0, stream>>>(
      Q_W, K_W, V_W, O_W, W1, W2, Q_b, K_b, V_b,
      BtQKh, BtQKl, BtVh, BtOh, BtOl, BtW1h, BtW2h, qkvb);
  // fused transpose + LN1: x -> ln1 h/l + xs h/l (all (B,S,C))
  ln1_fused<<<dim3(SS / 32, BB), tb32, 0, stream>>>(
      x, ln1g, ln1b, ln1h, ln1l, xsh, xsl);
  // fused QKV projection: QK split (hi+lo out), V plain -> vt (B,NH,HD,S)
  gemm_qkv<<<dim3(12, 64), 256, 0, stream>>>(
      ln1h, ln1l, BtAll, BtQKl, qkvb, qkh, qkl, vt);
  attn_mfma<<<dim3(SS / 64, NHH, BB), 256, 0, stream>>>(qkh, qkl, vt, oh);
  // O projection (B split) + residual(xs h+l) -> out1 fp32
  gemm64<1, 0, 0, 2, 0><<<dim3(8, 128), 256, 0, stream>>>(
      oh, BtOh, BtOl, O_b, nullptr, xsh, xsl, nullptr, out1, CC);
  ln_bf16_k<<<BB * SS, 256, 0, stream>>>(out1, ln2g, ln2b, ln2h);
  // MLP: W1 + exact GELU -> bf16
  gemm64<0, 1, 1, 0, 0><<<dim3(8, 128), 256, 0, stream>>>(
      ln2h, BtW1h, nullptr, b1, nullptr, nullptr, nullptr, geluh, nullptr, CC);
  // W2 + residual(out1 fp32) -> fp32, transposed epilogue writes (B,C,S)
  gemm64<0, 0, 0, 1, 1><<<dim3(8, 128), 256, 0, stream>>>(
      geluh, BtW2h, nullptr, b2, out1, nullptr, nullptr, nullptr, out, CC);
}

// Round 8
// 334.999 us; speedup vs baseline: 1.0136x; 1.0136x over previous
//
#include <hip/hip_runtime.h>
#include <math.h>

#define BB 8
#define CC 512
#define SS 1024
#define NHH 8
#define HDD 64
#define KD 512

typedef __attribute__((ext_vector_type(8))) short short8;
typedef __attribute__((ext_vector_type(4))) float f32x4;
typedef __attribute__((ext_vector_type(4))) unsigned short ushort4v;

__device__ __forceinline__ unsigned short f2bf(float x) {
  union { float f; unsigned int u; } c; c.f = x;
  unsigned int r = (c.u + 0x7FFFu + ((c.u >> 16) & 1u)) >> 16;
  return (unsigned short)r;
}
__device__ __forceinline__ float b2f(unsigned short h) {
  union { unsigned int u; float f; } c; c.u = ((unsigned int)h) << 16; return c.f;
}

#define GLD_LDS(gp, lp) __builtin_amdgcn_global_load_lds( \
    (const __attribute__((address_space(1))) void*)(gp),  \
    (__attribute__((address_space(3))) void*)(lp), 16, 0, 0)

// ---------- block-wide sum over 256 threads (4 waves) ----------
__device__ __forceinline__ float block_reduce_sum(float v) {
  __shared__ float sm[4];
  #pragma unroll
  for (int o = 32; o > 0; o >>= 1) v += __shfl_down(v, o, 64);
  if ((threadIdx.x & 63) == 0) sm[threadIdx.x >> 6] = v;
  __syncthreads();
  float r = (sm[0] + sm[1]) + (sm[2] + sm[3]);
  __syncthreads();
  return r;
}

// ---------- fused transpose + LayerNorm1: x (B,C,S) -> ln1 h/l + xs h/l ------
__global__ __launch_bounds__(256) void ln1_fused(
    const float* __restrict__ x, const float* __restrict__ g,
    const float* __restrict__ be,
    unsigned short* __restrict__ yh, unsigned short* __restrict__ yl,
    unsigned short* __restrict__ xh, unsigned short* __restrict__ xl) {
  __shared__ float tile[32][33];
  __shared__ float red[2][8][33];
  __shared__ float mu_s[32], rs_s[32];
  const int b = blockIdx.y, s0 = blockIdx.x * 32;
  const int tx = threadIdx.x, ty = threadIdx.y;
  const float* xb = x + (size_t)b * CC * SS;
  float psum = 0.f, psq = 0.f;
  for (int c0 = 0; c0 < CC; c0 += 32) {
    __syncthreads();
    #pragma unroll
    for (int i = ty; i < 32; i += 8)
      tile[i][tx] = xb[(size_t)(c0 + i) * SS + s0 + tx];
    __syncthreads();
    #pragma unroll
    for (int k = 0; k < 4; ++k) {
      const float v = tile[ty * 4 + k][tx];
      psum += v; psq += v * v;
    }
  }
  red[0][ty][tx] = psum; red[1][ty][tx] = psq;
  __syncthreads();
  if (ty == 0) {
    float s = 0.f, q = 0.f;
    #pragma unroll
    for (int k = 0; k < 8; ++k) { s += red[0][k][tx]; q += red[1][k][tx]; }
    const float mu = s * (1.0f / CC);
    mu_s[tx] = mu;
    rs_s[tx] = rsqrtf(q * (1.0f / CC) - mu * mu + 1e-5f);
  }
  __syncthreads();
  for (int c0 = 0; c0 < CC; c0 += 32) {
    __syncthreads();
    #pragma unroll
    for (int i = ty; i < 32; i += 8)
      tile[i][tx] = xb[(size_t)(c0 + i) * SS + s0 + tx];
    __syncthreads();
    const float gc = g[c0 + tx], bc = be[c0 + tx];
    #pragma unroll
    for (int i = ty; i < 32; i += 8) {
      const float v = tile[tx][i];  // c = c0+tx, s = s0+i
      const float y = (v - mu_s[i]) * rs_s[i] * gc + bc;
      const size_t oi = ((size_t)b * SS + s0 + i) * CC + c0 + tx;
      const unsigned short hy = f2bf(y);
      yh[oi] = hy; yl[oi] = f2bf(y - b2f(hy));
      const unsigned short hx = f2bf(v);
      xh[oi] = hx; xl[oi] = f2bf(v - b2f(hx));
    }
  }
}

// ---------- LayerNorm (C=512) contiguous rows -> bf16 hi ---------------------
__global__ __launch_bounds__(256) void ln_bf16_k(const float* __restrict__ in,
                                                 const float* __restrict__ g,
                                                 const float* __restrict__ be,
                                                 unsigned short* __restrict__ outh) {
  size_t row = blockIdx.x;
  const float* r = in + row * CC;
  int t = threadIdx.x;
  float v0 = r[t], v1 = r[t + 256];
  float s = block_reduce_sum(v0 + v1);
  float mu = s * (1.0f / CC);
  float d0 = v0 - mu, d1 = v1 - mu;
  float vs = block_reduce_sum(d0 * d0 + d1 * d1);
  float rstd = rsqrtf(vs * (1.0f / CC) + 1e-5f);
  outh[row * CC + t]       = f2bf(d0 * rstd * g[t] + be[t]);
  outh[row * CC + t + 256] = f2bf(d1 * rstd * g[t + 256] + be[t + 256]);
}

// ---------- weight convert: fp32 -> bf16 hi/lo B^T (N,K) ---------------------
__global__ __launch_bounds__(256) void convert_weights(
    const float* __restrict__ QW, const float* __restrict__ KW,
    const float* __restrict__ VW, const float* __restrict__ OW,
    const float* __restrict__ W1, const float* __restrict__ W2,
    const float* __restrict__ Qb, const float* __restrict__ Kb,
    const float* __restrict__ Vb,
    unsigned short* __restrict__ BtQKh, unsigned short* __restrict__ BtQKl,
    unsigned short* __restrict__ BtVh,
    unsigned short* __restrict__ BtOh, unsigned short* __restrict__ BtOl,
    unsigned short* __restrict__ BtW1h, unsigned short* __restrict__ BtW2h,
    float* __restrict__ qkvb) {
  __shared__ float tile[32][33];
  const int p = blockIdx.z, wsel = p >> 3, sub = p & 7;
  const int k0 = blockIdx.x * 32, d0 = blockIdx.y * 32;
  const int tx = threadIdx.x, ty = threadIdx.y;
  const float* w; int rs; unsigned short *dh, *dl; int nbase;
  switch (wsel) {
    case 0:  w = QW + sub * 32768; rs = 64;  dh = BtQKh; dl = BtQKl;  nbase = sub * 64;        break;
    case 1:  w = KW + sub * 32768; rs = 64;  dh = BtQKh; dl = BtQKl;  nbase = 512 + sub * 64;  break;
    case 2:  w = VW + sub * 32768; rs = 64;  dh = BtVh;  dl = nullptr; nbase = sub * 64;       break;
    case 3:  w = OW + sub * 64;    rs = 512; dh = BtOh;  dl = BtOl;   nbase = sub * 64;        break;
    case 4:  w = W1 + sub * 64;    rs = 512; dh = BtW1h; dl = nullptr; nbase = sub * 64;       break;
    default: w = W2 + sub * 64;    rs = 512; dh = BtW2h; dl = nullptr; nbase = sub * 64;       break;
  }
  for (int i = ty; i < 32; i += 8)
    tile[i][tx] = w[(size_t)(k0 + i) * rs + d0 + tx];
  __syncthreads();
  for (int i = ty; i < 32; i += 8) {
    float f = tile[tx][i];
    unsigned short h = f2bf(f);
    size_t idx = (size_t)(nbase + d0 + i) * KD + k0 + tx;
    dh[idx] = h;
    if (dl) dl[idx] = f2bf(f - b2f(h));
  }
  if (p == 0 && blockIdx.x == 0 && blockIdx.y == 0) {
    int t = ty * 32 + tx;
    for (int i = t; i < 1536; i += 256)
      qkvb[i] = i < 512 ? Qb[i] : (i < 1024 ? Kb[i - 512] : Vb[i - 1024]);
  }
}

// ---------- fused QKV projection GEMM, 128x128 tiles, xor-swizzled LDS -------
// V blocks: LDS-transposed epilogue -> vt (B, NH, HD, S) with coalesced stores.
__global__ __launch_bounds__(256) void gemm_qkv(
    const unsigned short* __restrict__ Ah, const unsigned short* __restrict__ Al,
    const unsigned short* __restrict__ Bth, const unsigned short* __restrict__ Btl,
    const float* __restrict__ bias,
    unsigned short* __restrict__ qkh, unsigned short* __restrict__ qkl,
    unsigned short* __restrict__ vt) {
  __shared__ __align__(16) unsigned short smem[4 * 128 * 32];  // As | Bs; ttile reuse
  unsigned short* As = smem;
  unsigned short* Bs = smem + 2 * 128 * 32;
  const int tid = threadIdx.x;
  const int w = tid >> 6, l = tid & 63, quad = l >> 4, lm = l & 15;
  const int n0 = blockIdx.x * 128, m0 = blockIdx.y * 128;
  const bool splitB = n0 < 1024;
  const int wm = (w >> 1) * 64, wn = (w & 1) * 64;
  const int srow = tid >> 2;
  const int sch = (((tid & 3) ^ (srow & 3)) * 8);
  const unsigned short* Agh = Ah + (size_t)(m0 + srow) * KD + sch;
  const unsigned short* Agl = Al + (size_t)(m0 + srow) * KD + sch;
  const unsigned short* Bgh = Bth + (size_t)(n0 + srow) * KD + sch;
  const unsigned short* Bgl = Btl + (size_t)(n0 + srow) * KD + sch;
  unsigned short* Aswh = As + w * 512;
  unsigned short* Aswl = As + 4096 + w * 512;
  unsigned short* Bswh = Bs + w * 512;
  unsigned short* Bswl = Bs + 4096 + w * 512;
  const int rch = ((quad ^ (lm & 3)) * 8);
  const f32x4 fzero = {0.f, 0.f, 0.f, 0.f};
  f32x4 acc[4][4];
  #pragma unroll
  for (int i = 0; i < 4; ++i)
    #pragma unroll
    for (int j = 0; j < 4; ++j) acc[i][j] = fzero;
  for (int k0 = 0; k0 < KD; k0 += 32) {
    __syncthreads();
    GLD_LDS(Agh + k0, Aswh);
    GLD_LDS(Agh + k0 + 64 * KD, Aswh + 2048);
    GLD_LDS(Agl + k0, Aswl);
    GLD_LDS(Agl + k0 + 64 * KD, Aswl + 2048);
    GLD_LDS(Bgh + k0, Bswh);
    GLD_LDS(Bgh + k0 + 64 * KD, Bswh + 2048);
    if (splitB) {
      GLD_LDS(Bgl + k0, Bswl);
      GLD_LDS(Bgl + k0 + 64 * KD, Bswl + 2048);
    }
    __syncthreads();
    short8 afh[4], afl[4], bfh[4], bfl[4];
    #pragma unroll
    for (int i = 0; i < 4; ++i) {
      afh[i] = *(const short8*)(As + (wm + i * 16 + lm) * 32 + rch);
      afl[i] = *(const short8*)(As + 4096 + (wm + i * 16 + lm) * 32 + rch);
    }
    #pragma unroll
    for (int j = 0; j < 4; ++j)
      bfh[j] = *(const short8*)(Bs + (wn + j * 16 + lm) * 32 + rch);
    if (splitB) {
      #pragma unroll
      for (int j = 0; j < 4; ++j)
        bfl[j] = *(const short8*)(Bs + 4096 + (wn + j * 16 + lm) * 32 + rch);
      #pragma unroll
      for (int i = 0; i < 4; ++i)
        #pragma unroll
        for (int j = 0; j < 4; ++j) {
          f32x4 t = acc[i][j];
          t = __builtin_amdgcn_mfma_f32_16x16x32_bf16(afh[i], bfh[j], t, 0, 0, 0);
          t = __builtin_amdgcn_mfma_f32_16x16x32_bf16(afh[i], bfl[j], t, 0, 0, 0);
          t = __builtin_amdgcn_mfma_f32_16x16x32_bf16(afl[i], bfh[j], t, 0, 0, 0);
          acc[i][j] = t;
        }
    } else {
      #pragma unroll
      for (int i = 0; i < 4; ++i)
        #pragma unroll
        for (int j = 0; j < 4; ++j)
          acc[i][j] = __builtin_amdgcn_mfma_f32_16x16x32_bf16(afh[i], bfh[j], acc[i][j], 0, 0, 0);
    }
  }
  if (splitB) {
    #pragma unroll
    for (int i = 0; i < 4; ++i) {
      const int row = m0 + wm + i * 16 + quad * 4;
      #pragma unroll
      for (int j = 0; j < 4; ++j) {
        const int ncol = n0 + wn + j * 16 + lm;
        const float bv = bias[ncol];
        #pragma unroll
        for (int r = 0; r < 4; ++r) {
          const float xv = acc[i][j][r] + bv;
          const size_t oi = (size_t)(row + r) * 1024 + ncol;
          unsigned short h = f2bf(xv);
          qkh[oi] = h;
          qkl[oi] = f2bf(xv - b2f(h));
        }
      }
    }
  } else {
    // V: bf16 values -> swizzled 128x128 LDS tile -> coalesced (B,NH,HD,S) stores
    __syncthreads();  // As/Bs fragment reads done; smem becomes ttile
    #pragma unroll
    for (int i = 0; i < 4; ++i) {
      const int mlb = wm + i * 16 + quad * 4;        // m (s) base, %8 in {0,4}
      #pragma unroll
      for (int j = 0; j < 4; ++j) {
        const int nl = wn + j * 16 + lm;             // 0..127 (head-dim col)
        const float bv = bias[n0 + nl];
        ushort4v pk;
        #pragma unroll
        for (int r = 0; r < 4; ++r) pk[r] = f2bf(acc[i][j][r] + bv);
        const int chunk = ((mlb >> 3) ^ (nl & 15));
        *(ushort4v*)(smem + nl * 128 + chunk * 8 + (mlb & 7)) = pk;
      }
    }
    __syncthreads();
    const int tn = tid >> 4, tc = tid & 15;
    const int bb2 = m0 >> 10, sbase = m0 & 1023;
    #pragma unroll
    for (int pass = 0; pass < 8; ++pass) {
      const int nl = pass * 16 + tn;
      const int hh = (n0 - 1024 + nl) >> 6, dd = nl & 63;
      short8 v8 = *(const short8*)(smem + nl * 128 + ((tc ^ (nl & 15)) * 8));
      *(short8*)(vt + ((size_t)(bb2 * 8 + hh) * 64 + dd) * 1024 + sbase + tc * 8) = v8;
    }
  }
}

// ---------- 64x64-tile GEMM, xor-swizzled --------------------------------
// RESID: 0 none, 1 fp32 ptr, 2 bf16 h+l pair. TRANS: write (B,C,S) via LDS.
template<int SB, int GELU, int OUTMODE, int RESID, int TRANS>
__global__ __launch_bounds__(256) void gemm64(
    const unsigned short* __restrict__ Ah,
    const unsigned short* __restrict__ Bh, const unsigned short* __restrict__ Bl,
    const float* __restrict__ bias, const float* __restrict__ residf,
    const unsigned short* __restrict__ residh, const unsigned short* __restrict__ residl,
    unsigned short* __restrict__ outh, float* __restrict__ outf, int ldc) {
  __shared__ __align__(16) unsigned short As[64 * 32];
  __shared__ __align__(16) unsigned short Bs[(SB ? 2 : 1) * 64 * 32];
  __shared__ float ttile[TRANS ? 64 : 1][TRANS ? 65 : 1];
  const int tid = threadIdx.x;
  const int w = tid >> 6, l = tid & 63, quad = l >> 4, lm = l & 15;
  const int n0 = blockIdx.x * 64, m0 = blockIdx.y * 64;
  const int wm = (w >> 1) * 32, wn = (w & 1) * 32;
  const int srow = tid >> 2;
  const int sch = (((tid & 3) ^ (srow & 3)) * 8);
  const unsigned short* Ag = Ah + (size_t)(m0 + srow) * KD + sch;
  const unsigned short* Bg = Bh + (size_t)(n0 + srow) * KD + sch;
  const unsigned short* Bgl = SB ? Bl + (size_t)(n0 + srow) * KD + sch : nullptr;
  unsigned short* Asw = As + w * 512;
  unsigned short* Bsw = Bs + w * 512;
  unsigned short* Bswl = Bs + 2048 + w * 512;
  const int rch = ((quad ^ (lm & 3)) * 8);
  const f32x4 fzero = {0.f, 0.f, 0.f, 0.f};
  f32x4 acc[2][2];
  #pragma unroll
  for (int i = 0; i < 2; ++i)
    #pragma unroll
    for (int j = 0; j < 2; ++j) acc[i][j] = fzero;
  for (int k0 = 0; k0 < KD; k0 += 32) {
    __syncthreads();
    GLD_LDS(Ag + k0, Asw);
    GLD_LDS(Bg + k0, Bsw);
    if constexpr (SB) GLD_LDS(Bgl + k0, Bswl);
    __syncthreads();
    short8 af[2], bfh[2], bfl[2];
    #pragma unroll
    for (int i = 0; i < 2; ++i)
      af[i] = *(const short8*)(As + (wm + i * 16 + lm) * 32 + rch);
    #pragma unroll
    for (int j = 0; j < 2; ++j)
      bfh[j] = *(const short8*)(Bs + (wn + j * 16 + lm) * 32 + rch);
    if constexpr (SB) {
      #pragma unroll
      for (int j = 0; j < 2; ++j)
        bfl[j] = *(const short8*)(Bs + 2048 + (wn + j * 16 + lm) * 32 + rch);
    }
    #pragma unroll
    for (int i = 0; i < 2; ++i)
      #pragma unroll
      for (int j = 0; j < 2; ++j) {
        f32x4 t = acc[i][j];
        t = __builtin_amdgcn_mfma_f32_16x16x32_bf16(af[i], bfh[j], t, 0, 0, 0);
        if constexpr (SB)
          t = __builtin_amdgcn_mfma_f32_16x16x32_bf16(af[i], bfl[j], t, 0, 0, 0);
        acc[i][j] = t;
      }
  }
  if constexpr (TRANS) __syncthreads();
  #pragma unroll
  for (int i = 0; i < 2; ++i) {
    const int row = m0 + wm + i * 16 + quad * 4;
    #pragma unroll
    for (int j = 0; j < 2; ++j) {
      const int col = n0 + wn + j * 16 + lm;
      const float bv = bias[col];
      #pragma unroll
      for (int r = 0; r < 4; ++r) {
        float x = acc[i][j][r] + bv;
        if (GELU) x = 0.5f * x * (1.0f + erff(x * 0.70710678118654752f));
        const size_t ri = (size_t)(row + r) * CC + col;
        if (RESID == 1) x += residf[ri];
        if (RESID == 2) x += b2f(residh[ri]) + b2f(residl[ri]);
        if constexpr (TRANS) {
          ttile[wm + i * 16 + quad * 4 + r][wn + j * 16 + lm] = x;
        } else {
          const size_t oi = (size_t)(row + r) * ldc + col;
          if (OUTMODE == 0) outf[oi] = x;
          else outh[oi] = f2bf(x);
        }
      }
    }
  }
  if constexpr (TRANS) {
    __syncthreads();
    const int bi = m0 >> 10, s0 = m0 & 1023;
    const int s = tid & 63;
    #pragma unroll
    for (int c0 = 0; c0 < 64; c0 += 4) {
      const int col = c0 + (tid >> 6);
      outf[(size_t)(bi * 512 + n0 + col) * 1024 + s0 + s] = ttile[s][col];
    }
  }
}

// ---------- flash attention: GLD_LDS K & V^T staging, exp2 softmax -----------
// QK hi/lo: (B, S, 1024) [Q | K]; Vt: (B, NH, HD, S); O: (B, S, 512) bf16
__global__ __launch_bounds__(256) void attn_mfma(
    const unsigned short* __restrict__ QKh, const unsigned short* __restrict__ QKl,
    const unsigned short* __restrict__ Vt, unsigned short* __restrict__ Oh) {
  __shared__ __align__(16) unsigned short Ksh[64 * 64], Ksl[64 * 64];
  __shared__ __align__(16) unsigned short Vts[64 * 64];
  __shared__ __align__(16) unsigned short Ps[4 * 16 * 88];
  const int q0 = blockIdx.x * 64, h = blockIdx.y, b = blockIdx.z;
  const int tid = threadIdx.x, w = tid >> 6, l = tid & 63, quad = l >> 4, lm = l & 15;
  const int LDQ = 2 * CC;
  const size_t qkbase = (size_t)b * SS * LDQ;
  const int srow8 = tid >> 3;                       // 0..31
  const int sch8  = ((tid & 7) ^ (srow8 & 7)) * 8;  // xor-swizzled chunk (shorts)
  const unsigned short* Vg = Vt + ((size_t)(b * 8 + h) * 64 + srow8) * 1024 + sch8;
  short8 qh[2], ql[2];
  {
    const size_t qo = qkbase + (size_t)(q0 + w * 16 + lm) * LDQ + h * 64 + quad * 8;
    qh[0] = *(const short8*)(QKh + qo);
    qh[1] = *(const short8*)(QKh + qo + 32);
    ql[0] = *(const short8*)(QKl + qo);
    ql[1] = *(const short8*)(QKl + qo + 32);
  }
  short8 bones;
  #pragma unroll
  for (int u = 0; u < 8; ++u) bones[u] = (lm == 0) ? (short)0x3F80 : (short)0;
  const f32x4 fzero = {0.f, 0.f, 0.f, 0.f};
  float mrow[4];
  f32x4 oacc[5];  // [0..3]=O cols, [4]=row-sum
  #pragma unroll
  for (int r = 0; r < 4; ++r) mrow[r] = -1e30f;
  #pragma unroll
  for (int j = 0; j < 5; ++j) oacc[j] = fzero;
  const float scale = 0.044194173824159216f * 1.4426950408889634f;
  unsigned short* Pw = Ps + w * (16 * 88);
  for (int kt = 0; kt < SS; kt += 64) {
    __syncthreads();
    {
      const unsigned short* kg  = QKh + qkbase + (size_t)(kt + srow8) * LDQ + CC + h * 64 + sch8;
      const unsigned short* kgl = QKl + qkbase + (size_t)(kt + srow8) * LDQ + CC + h * 64 + sch8;
      GLD_LDS(kg, Ksh + w * 512);
      GLD_LDS(kg + 32 * LDQ, Ksh + 2048 + w * 512);
      GLD_LDS(kgl, Ksl + w * 512);
      GLD_LDS(kgl + 32 * LDQ, Ksl + 2048 + w * 512);
      GLD_LDS(Vg + kt, Vts + w * 512);
      GLD_LDS(Vg + kt + 32 * 1024, Vts + 2048 + w * 512);
    }
    __syncthreads();
    f32x4 sc[4];
    #pragma unroll
    for (int j = 0; j < 4; ++j) sc[j] = fzero;
    #pragma unroll
    for (int st = 0; st < 2; ++st) {
      const int kc = ((st * 4 + quad) ^ (lm & 7)) * 8;
      #pragma unroll
      for (int j = 0; j < 4; ++j) {
        short8 kh = *(const short8*)(Ksh + (j * 16 + lm) * 64 + kc);
        short8 kl = *(const short8*)(Ksl + (j * 16 + lm) * 64 + kc);
        f32x4 t = sc[j];
        t = __builtin_amdgcn_mfma_f32_16x16x32_bf16(qh[st], kh, t, 0, 0, 0);
        t = __builtin_amdgcn_mfma_f32_16x16x32_bf16(qh[st], kl, t, 0, 0, 0);
        t = __builtin_amdgcn_mfma_f32_16x16x32_bf16(ql[st], kh, t, 0, 0, 0);
        sc[j] = t;
      }
    }
    #pragma unroll
    for (int j = 0; j < 4; ++j) sc[j] *= scale;
    #pragma unroll
    for (int r = 0; r < 4; ++r) {
      float mt = fmaxf(fmaxf(sc[0][r], sc[1][r]), fmaxf(sc[2][r], sc[3][r]));
      #pragma unroll
      for (int mask = 1; mask < 16; mask <<= 1) mt = fmaxf(mt, __shfl_xor(mt, mask, 64));
      const float mn = fmaxf(mrow[r], mt);
      const float alpha = exp2f(mrow[r] - mn);
      mrow[r] = mn;
      #pragma unroll
      for (int j = 0; j < 4; ++j) sc[j][r] = exp2f(sc[j][r] - mn);
      #pragma unroll
      for (int j = 0; j < 5; ++j) oacc[j][r] *= alpha;
    }
    #pragma unroll
    for (int r = 0; r < 4; ++r)
      #pragma unroll
      for (int j = 0; j < 4; ++j)
        Pw[(quad * 4 + r) * 88 + j * 16 + lm] = f2bf(sc[j][r]);
    #pragma unroll
    for (int st = 0; st < 2; ++st) {
      short8 ap = *(const short8*)(Pw + lm * 88 + st * 32 + quad * 8);
      const int kc = ((st * 4 + quad) ^ (lm & 7)) * 8;
      #pragma unroll
      for (int j = 0; j < 4; ++j) {
        short8 vv = *(const short8*)(Vts + (j * 16 + lm) * 64 + kc);
        oacc[j] = __builtin_amdgcn_mfma_f32_16x16x32_bf16(ap, vv, oacc[j], 0, 0, 0);
      }
      oacc[4] = __builtin_amdgcn_mfma_f32_16x16x32_bf16(ap, bones, oacc[4], 0, 0, 0);
    }
  }
  float inv[4];
  #pragma unroll
  for (int r = 0; r < 4; ++r) {
    const float lv = __shfl(oacc[4][r], l & 48, 64);
    inv[r] = 1.f / lv;
  }
  const size_t obase =
      (size_t)b * SS * CC + (size_t)(q0 + w * 16 + quad * 4) * CC + h * 64 + lm;
  #pragma unroll
  for (int j = 0; j < 4; ++j)
    #pragma unroll
    for (int r = 0; r < 4; ++r)
      Oh[obase + (size_t)r * CC + j * 16] = f2bf(oacc[j][r] * inv[r]);
}

extern "C" void kernel_launch(void* const* d_in, const int* in_sizes, int n_in,
                              void* d_out, int out_size, void* d_ws, size_t ws_size,
                              hipStream_t stream) {
  const float* x    = (const float*)d_in[0];
  const float* K_W  = (const float*)d_in[2];
  const float* K_b  = (const float*)d_in[3];
  const float* Q_W  = (const float*)d_in[4];
  const float* Q_b  = (const float*)d_in[5];
  const float* V_W  = (const float*)d_in[6];
  const float* V_b  = (const float*)d_in[7];
  const float* O_W  = (const float*)d_in[8];
  const float* O_b  = (const float*)d_in[9];
  const float* ln1g = (const float*)d_in[10];
  const float* ln1b = (const float*)d_in[11];
  const float* ln2g = (const float*)d_in[12];
  const float* ln2b = (const float*)d_in[13];
  const float* W1   = (const float*)d_in[14];
  const float* b1   = (const float*)d_in[15];
  const float* W2   = (const float*)d_in[16];
  const float* b2   = (const float*)d_in[17];
  float* out = (float*)d_out;

  unsigned char* ws = (unsigned char*)d_ws;
  const size_t MB = 1u << 20;
  unsigned short* qkh   = (unsigned short*)(ws);             // (B,S,1024) 16MB
  unsigned short* qkl   = (unsigned short*)(ws + 16 * MB);   // 16MB
  unsigned short* vt    = (unsigned short*)(ws + 32 * MB);   // (B,NH,HD,S) 8MB
  unsigned short* ln1h  = (unsigned short*)(ws + 40 * MB);   // 8MB
  unsigned short* ln1l  = (unsigned short*)(ws + 48 * MB);   // 8MB
  unsigned short* xsh   = (unsigned short*)(ws + 56 * MB);   // 8MB (residual hi)
  unsigned short* xsl   = (unsigned short*)(ws + 64 * MB);   // 8MB (residual lo)
  unsigned short* oh    = ln1h;                              // reuse after QKV GEMM
  float* out1           = (float*)(ws + 72 * MB);            // 16MB fp32 residual
  unsigned short* ln2h  = qkh;                               // reuse (qk dead post-attn)
  unsigned short* geluh = (unsigned short*)(ws + 8 * MB);    // reuse qkh 2nd half
  unsigned short* BtAll = (unsigned short*)(ws + 88 * MB);   // [QKh 1024 | Vh 512] x 512
  unsigned short* BtQKh = BtAll;
  unsigned short* BtVh  = BtAll + 1024 * 512;
  unsigned short* BtQKl = BtVh + 512 * 512;
  unsigned short* BtOh  = BtQKl + 1024 * 512;
  unsigned short* BtOl  = BtOh + 512 * 512;
  unsigned short* BtW1h = BtOl + 512 * 512;
  unsigned short* BtW2h = BtW1h + 512 * 512;
  float* qkvb           = (float*)(BtW2h + 512 * 512);

  dim3 tb32(32, 8);
  convert_weights<<<dim3(16, 2, 48), tb32, 0, stream>>>(
      Q_W, K_W, V_W, O_W, W1, W2, Q_b, K_b, V_b,
      BtQKh, BtQKl, BtVh, BtOh, BtOl, BtW1h, BtW2h, qkvb);
  ln1_fused<<<dim3(SS / 32, BB), tb32, 0, stream>>>(
      x, ln1g, ln1b, ln1h, ln1l, xsh, xsl);
  gemm_qkv<<<dim3(12, 64), 256, 0, stream>>>(
      ln1h, ln1l, BtAll, BtQKl, qkvb, qkh, qkl, vt);
  attn_mfma<<<dim3(SS / 64, NHH, BB), 256, 0, stream>>>(qkh, qkl, vt, oh);
  gemm64<1, 0, 0, 2, 0><<<dim3(8, 128), 256, 0, stream>>>(
      oh, BtOh, BtOl, O_b, nullptr, xsh, xsl, nullptr, out1, CC);
  ln_bf16_k<<<BB * SS, 256, 0, stream>>>(out1, ln2g, ln2b, ln2h);
  gemm64<0, 1, 1, 0, 0><<<dim3(8, 128), 256, 0, stream>>>(
      ln2h, BtW1h, nullptr, b1, nullptr, nullptr, nullptr, geluh, nullptr, CC);
  gemm64<0, 0, 0, 1, 1><<<dim3(8, 128), 256, 0, stream>>>(
      geluh, BtW2h, nullptr, b2, out1, nullptr, nullptr, nullptr, out, CC);
}

// Round 9
// 307.519 us; speedup vs baseline: 1.1041x; 1.0894x over previous
//
#include <hip/hip_runtime.h>
#include <math.h>

#define BB 8
#define CC 512
#define SS 1024
#define NHH 8
#define HDD 64
#define KD 512

typedef __attribute__((ext_vector_type(8))) short short8;
typedef __attribute__((ext_vector_type(4))) float f32x4;
typedef __attribute__((ext_vector_type(4))) unsigned short ushort4v;

__device__ __forceinline__ unsigned short f2bf(float x) {
  union { float f; unsigned int u; } c; c.f = x;
  unsigned int r = (c.u + 0x7FFFu + ((c.u >> 16) & 1u)) >> 16;
  return (unsigned short)r;
}
__device__ __forceinline__ float b2f(unsigned short h) {
  union { unsigned int u; float f; } c; c.u = ((unsigned int)h) << 16; return c.f;
}

#define GLD_LDS(gp, lp) __builtin_amdgcn_global_load_lds( \
    (const __attribute__((address_space(1))) void*)(gp),  \
    (__attribute__((address_space(3))) void*)(lp), 16, 0, 0)

// ---------- block-wide sum over 256 threads (4 waves) ----------
__device__ __forceinline__ float block_reduce_sum(float v) {
  __shared__ float sm[4];
  #pragma unroll
  for (int o = 32; o > 0; o >>= 1) v += __shfl_down(v, o, 64);
  if ((threadIdx.x & 63) == 0) sm[threadIdx.x >> 6] = v;
  __syncthreads();
  float r = (sm[0] + sm[1]) + (sm[2] + sm[3]);
  __syncthreads();
  return r;
}

// ---------- LN1 stats: x (B,C,S) -> (mu, rstd) per (b,s) ---------------------
// grid (SS/64, BB); thread (s-lane, c-group): 128 coalesced strided loads
__global__ __launch_bounds__(256) void ln1_stats(const float* __restrict__ x,
                                                 float2* __restrict__ mustd) {
  const int b = blockIdx.y, s0 = blockIdx.x * 64;
  const int sl = threadIdx.x & 63, cg = threadIdx.x >> 6;  // 4 c-groups x 128
  const float* xp = x + (size_t)b * CC * SS + s0 + sl;
  float ps = 0.f, pq = 0.f;
  #pragma unroll 8
  for (int i = 0; i < 128; ++i) {
    const float v = xp[(size_t)(cg * 128 + i) * SS];
    ps += v; pq += v * v;
  }
  __shared__ float sred[2][4][64];
  sred[0][cg][sl] = ps; sred[1][cg][sl] = pq;
  __syncthreads();
  if (cg == 0) {
    const float s = (sred[0][0][sl] + sred[0][1][sl]) + (sred[0][2][sl] + sred[0][3][sl]);
    const float q = (sred[1][0][sl] + sred[1][1][sl]) + (sred[1][2][sl] + sred[1][3][sl]);
    const float mu = s * (1.0f / CC);
    const float rs = rsqrtf(q * (1.0f / CC) - mu * mu + 1e-5f);
    mustd[b * SS + s0 + sl] = make_float2(mu, rs);
  }
}

// ---------- LN1 apply + transpose: -> ln1 h/l + xs h/l (B,S,C) ---------------
// transpose-style tiles, grid (SS/32, CC/32, BB)
__global__ __launch_bounds__(256) void ln1_apply(
    const float* __restrict__ x, const float2* __restrict__ mustd,
    const float* __restrict__ g, const float* __restrict__ be,
    unsigned short* __restrict__ yh, unsigned short* __restrict__ yl,
    unsigned short* __restrict__ xh, unsigned short* __restrict__ xl) {
  __shared__ float tile[32][33];
  const int b = blockIdx.z, c0 = blockIdx.y * 32, s0 = blockIdx.x * 32;
  const int tx = threadIdx.x, ty = threadIdx.y;  // (32, 8)
  const float* xb = x + ((size_t)b * CC + c0) * SS + s0;
  #pragma unroll
  for (int i = ty; i < 32; i += 8)
    tile[i][tx] = xb[(size_t)i * SS + tx];
  __syncthreads();
  const float gc = g[c0 + tx], bc = be[c0 + tx];
  #pragma unroll
  for (int i = ty; i < 32; i += 8) {
    const float2 ms = mustd[b * SS + s0 + i];
    const float v = tile[tx][i];  // c = c0+tx, s = s0+i
    const float y = (v - ms.x) * ms.y * gc + bc;
    const size_t oi = ((size_t)b * SS + s0 + i) * CC + c0 + tx;
    const unsigned short hy = f2bf(y);
    yh[oi] = hy; yl[oi] = f2bf(y - b2f(hy));
    const unsigned short hx = f2bf(v);
    xh[oi] = hx; xl[oi] = f2bf(v - b2f(hx));
  }
}

// ---------- LayerNorm (C=512) contiguous rows -> bf16 hi ---------------------
__global__ __launch_bounds__(256) void ln_bf16_k(const float* __restrict__ in,
                                                 const float* __restrict__ g,
                                                 const float* __restrict__ be,
                                                 unsigned short* __restrict__ outh) {
  size_t row = blockIdx.x;
  const float* r = in + row * CC;
  int t = threadIdx.x;
  float v0 = r[t], v1 = r[t + 256];
  float s = block_reduce_sum(v0 + v1);
  float mu = s * (1.0f / CC);
  float d0 = v0 - mu, d1 = v1 - mu;
  float vs = block_reduce_sum(d0 * d0 + d1 * d1);
  float rstd = rsqrtf(vs * (1.0f / CC) + 1e-5f);
  outh[row * CC + t]       = f2bf(d0 * rstd * g[t] + be[t]);
  outh[row * CC + t + 256] = f2bf(d1 * rstd * g[t + 256] + be[t + 256]);
}

// ---------- weight convert: fp32 -> bf16 hi/lo B^T (N,K) ---------------------
__global__ __launch_bounds__(256) void convert_weights(
    const float* __restrict__ QW, const float* __restrict__ KW,
    const float* __restrict__ VW, const float* __restrict__ OW,
    const float* __restrict__ W1, const float* __restrict__ W2,
    const float* __restrict__ Qb, const float* __restrict__ Kb,
    const float* __restrict__ Vb,
    unsigned short* __restrict__ BtQKh, unsigned short* __restrict__ BtQKl,
    unsigned short* __restrict__ BtVh,
    unsigned short* __restrict__ BtOh, unsigned short* __restrict__ BtOl,
    unsigned short* __restrict__ BtW1h, unsigned short* __restrict__ BtW2h,
    float* __restrict__ qkvb) {
  __shared__ float tile[32][33];
  const int p = blockIdx.z, wsel = p >> 3, sub = p & 7;
  const int k0 = blockIdx.x * 32, d0 = blockIdx.y * 32;
  const int tx = threadIdx.x, ty = threadIdx.y;
  const float* w; int rs; unsigned short *dh, *dl; int nbase;
  switch (wsel) {
    case 0:  w = QW + sub * 32768; rs = 64;  dh = BtQKh; dl = BtQKl;  nbase = sub * 64;        break;
    case 1:  w = KW + sub * 32768; rs = 64;  dh = BtQKh; dl = BtQKl;  nbase = 512 + sub * 64;  break;
    case 2:  w = VW + sub * 32768; rs = 64;  dh = BtVh;  dl = nullptr; nbase = sub * 64;       break;
    case 3:  w = OW + sub * 64;    rs = 512; dh = BtOh;  dl = BtOl;   nbase = sub * 64;        break;
    case 4:  w = W1 + sub * 64;    rs = 512; dh = BtW1h; dl = nullptr; nbase = sub * 64;       break;
    default: w = W2 + sub * 64;    rs = 512; dh = BtW2h; dl = nullptr; nbase = sub * 64;       break;
  }
  for (int i = ty; i < 32; i += 8)
    tile[i][tx] = w[(size_t)(k0 + i) * rs + d0 + tx];
  __syncthreads();
  for (int i = ty; i < 32; i += 8) {
    float f = tile[tx][i];
    unsigned short h = f2bf(f);
    size_t idx = (size_t)(nbase + d0 + i) * KD + k0 + tx;
    dh[idx] = h;
    if (dl) dl[idx] = f2bf(f - b2f(h));
  }
  if (p == 0 && blockIdx.x == 0 && blockIdx.y == 0) {
    int t = ty * 32 + tx;
    for (int i = t; i < 1536; i += 256)
      qkvb[i] = i < 512 ? Qb[i] : (i < 1024 ? Kb[i - 512] : Vb[i - 1024]);
  }
}

// ---------- fused QKV projection GEMM, 128x128 tiles, xor-swizzled LDS -------
// V blocks: LDS-transposed epilogue -> vt (B, NH, HD, S) with coalesced stores.
__global__ __launch_bounds__(256) void gemm_qkv(
    const unsigned short* __restrict__ Ah, const unsigned short* __restrict__ Al,
    const unsigned short* __restrict__ Bth, const unsigned short* __restrict__ Btl,
    const float* __restrict__ bias,
    unsigned short* __restrict__ qkh, unsigned short* __restrict__ qkl,
    unsigned short* __restrict__ vt) {
  __shared__ __align__(16) unsigned short smem[4 * 128 * 32];  // As | Bs; ttile reuse
  unsigned short* As = smem;
  unsigned short* Bs = smem + 2 * 128 * 32;
  const int tid = threadIdx.x;
  const int w = tid >> 6, l = tid & 63, quad = l >> 4, lm = l & 15;
  const int n0 = blockIdx.x * 128, m0 = blockIdx.y * 128;
  const bool splitB = n0 < 1024;
  const int wm = (w >> 1) * 64, wn = (w & 1) * 64;
  const int srow = tid >> 2;
  const int sch = (((tid & 3) ^ (srow & 3)) * 8);
  const unsigned short* Agh = Ah + (size_t)(m0 + srow) * KD + sch;
  const unsigned short* Agl = Al + (size_t)(m0 + srow) * KD + sch;
  const unsigned short* Bgh = Bth + (size_t)(n0 + srow) * KD + sch;
  const unsigned short* Bgl = Btl + (size_t)(n0 + srow) * KD + sch;
  unsigned short* Aswh = As + w * 512;
  unsigned short* Aswl = As + 4096 + w * 512;
  unsigned short* Bswh = Bs + w * 512;
  unsigned short* Bswl = Bs + 4096 + w * 512;
  const int rch = ((quad ^ (lm & 3)) * 8);
  const f32x4 fzero = {0.f, 0.f, 0.f, 0.f};
  f32x4 acc[4][4];
  #pragma unroll
  for (int i = 0; i < 4; ++i)
    #pragma unroll
    for (int j = 0; j < 4; ++j) acc[i][j] = fzero;
  for (int k0 = 0; k0 < KD; k0 += 32) {
    __syncthreads();
    GLD_LDS(Agh + k0, Aswh);
    GLD_LDS(Agh + k0 + 64 * KD, Aswh + 2048);
    GLD_LDS(Agl + k0, Aswl);
    GLD_LDS(Agl + k0 + 64 * KD, Aswl + 2048);
    GLD_LDS(Bgh + k0, Bswh);
    GLD_LDS(Bgh + k0 + 64 * KD, Bswh + 2048);
    if (splitB) {
      GLD_LDS(Bgl + k0, Bswl);
      GLD_LDS(Bgl + k0 + 64 * KD, Bswl + 2048);
    }
    __syncthreads();
    short8 afh[4], afl[4], bfh[4], bfl[4];
    #pragma unroll
    for (int i = 0; i < 4; ++i) {
      afh[i] = *(const short8*)(As + (wm + i * 16 + lm) * 32 + rch);
      afl[i] = *(const short8*)(As + 4096 + (wm + i * 16 + lm) * 32 + rch);
    }
    #pragma unroll
    for (int j = 0; j < 4; ++j)
      bfh[j] = *(const short8*)(Bs + (wn + j * 16 + lm) * 32 + rch);
    if (splitB) {
      #pragma unroll
      for (int j = 0; j < 4; ++j)
        bfl[j] = *(const short8*)(Bs + 4096 + (wn + j * 16 + lm) * 32 + rch);
      #pragma unroll
      for (int i = 0; i < 4; ++i)
        #pragma unroll
        for (int j = 0; j < 4; ++j) {
          f32x4 t = acc[i][j];
          t = __builtin_amdgcn_mfma_f32_16x16x32_bf16(afh[i], bfh[j], t, 0, 0, 0);
          t = __builtin_amdgcn_mfma_f32_16x16x32_bf16(afh[i], bfl[j], t, 0, 0, 0);
          t = __builtin_amdgcn_mfma_f32_16x16x32_bf16(afl[i], bfh[j], t, 0, 0, 0);
          acc[i][j] = t;
        }
    } else {
      #pragma unroll
      for (int i = 0; i < 4; ++i)
        #pragma unroll
        for (int j = 0; j < 4; ++j)
          acc[i][j] = __builtin_amdgcn_mfma_f32_16x16x32_bf16(afh[i], bfh[j], acc[i][j], 0, 0, 0);
    }
  }
  if (splitB) {
    #pragma unroll
    for (int i = 0; i < 4; ++i) {
      const int row = m0 + wm + i * 16 + quad * 4;
      #pragma unroll
      for (int j = 0; j < 4; ++j) {
        const int ncol = n0 + wn + j * 16 + lm;
        const float bv = bias[ncol];
        #pragma unroll
        for (int r = 0; r < 4; ++r) {
          const float xv = acc[i][j][r] + bv;
          const size_t oi = (size_t)(row + r) * 1024 + ncol;
          unsigned short h = f2bf(xv);
          qkh[oi] = h;
          qkl[oi] = f2bf(xv - b2f(h));
        }
      }
    }
  } else {
    // V: bf16 values -> swizzled 128x128 LDS tile -> coalesced (B,NH,HD,S) stores
    __syncthreads();
    #pragma unroll
    for (int i = 0; i < 4; ++i) {
      const int mlb = wm + i * 16 + quad * 4;
      #pragma unroll
      for (int j = 0; j < 4; ++j) {
        const int nl = wn + j * 16 + lm;
        const float bv = bias[n0 + nl];
        ushort4v pk;
        #pragma unroll
        for (int r = 0; r < 4; ++r) pk[r] = f2bf(acc[i][j][r] + bv);
        const int chunk = ((mlb >> 3) ^ (nl & 15));
        *(ushort4v*)(smem + nl * 128 + chunk * 8 + (mlb & 7)) = pk;
      }
    }
    __syncthreads();
    const int tn = tid >> 4, tc = tid & 15;
    const int bb2 = m0 >> 10, sbase = m0 & 1023;
    #pragma unroll
    for (int pass = 0; pass < 8; ++pass) {
      const int nl = pass * 16 + tn;
      const int hh = (n0 - 1024 + nl) >> 6, dd = nl & 63;
      short8 v8 = *(const short8*)(smem + nl * 128 + ((tc ^ (nl & 15)) * 8));
      *(short8*)(vt + ((size_t)(bb2 * 8 + hh) * 64 + dd) * 1024 + sbase + tc * 8) = v8;
    }
  }
}

// ---------- 64x64-tile GEMM, xor-swizzled --------------------------------
// RESID: 0 none, 1 fp32 ptr, 2 bf16 h+l pair. TRANS: write (B,C,S) via LDS.
template<int SB, int GELU, int OUTMODE, int RESID, int TRANS>
__global__ __launch_bounds__(256) void gemm64(
    const unsigned short* __restrict__ Ah,
    const unsigned short* __restrict__ Bh, const unsigned short* __restrict__ Bl,
    const float* __restrict__ bias, const float* __restrict__ residf,
    const unsigned short* __restrict__ residh, const unsigned short* __restrict__ residl,
    unsigned short* __restrict__ outh, float* __restrict__ outf, int ldc) {
  __shared__ __align__(16) unsigned short As[64 * 32];
  __shared__ __align__(16) unsigned short Bs[(SB ? 2 : 1) * 64 * 32];
  __shared__ float ttile[TRANS ? 64 : 1][TRANS ? 65 : 1];
  const int tid = threadIdx.x;
  const int w = tid >> 6, l = tid & 63, quad = l >> 4, lm = l & 15;
  const int n0 = blockIdx.x * 64, m0 = blockIdx.y * 64;
  const int wm = (w >> 1) * 32, wn = (w & 1) * 32;
  const int srow = tid >> 2;
  const int sch = (((tid & 3) ^ (srow & 3)) * 8);
  const unsigned short* Ag = Ah + (size_t)(m0 + srow) * KD + sch;
  const unsigned short* Bg = Bh + (size_t)(n0 + srow) * KD + sch;
  const unsigned short* Bgl = SB ? Bl + (size_t)(n0 + srow) * KD + sch : nullptr;
  unsigned short* Asw = As + w * 512;
  unsigned short* Bsw = Bs + w * 512;
  unsigned short* Bswl = Bs + 2048 + w * 512;
  const int rch = ((quad ^ (lm & 3)) * 8);
  const f32x4 fzero = {0.f, 0.f, 0.f, 0.f};
  f32x4 acc[2][2];
  #pragma unroll
  for (int i = 0; i < 2; ++i)
    #pragma unroll
    for (int j = 0; j < 2; ++j) acc[i][j] = fzero;
  for (int k0 = 0; k0 < KD; k0 += 32) {
    __syncthreads();
    GLD_LDS(Ag + k0, Asw);
    GLD_LDS(Bg + k0, Bsw);
    if constexpr (SB) GLD_LDS(Bgl + k0, Bswl);
    __syncthreads();
    short8 af[2], bfh[2], bfl[2];
    #pragma unroll
    for (int i = 0; i < 2; ++i)
      af[i] = *(const short8*)(As + (wm + i * 16 + lm) * 32 + rch);
    #pragma unroll
    for (int j = 0; j < 2; ++j)
      bfh[j] = *(const short8*)(Bs + (wn + j * 16 + lm) * 32 + rch);
    if constexpr (SB) {
      #pragma unroll
      for (int j = 0; j < 2; ++j)
        bfl[j] = *(const short8*)(Bs + 2048 + (wn + j * 16 + lm) * 32 + rch);
    }
    #pragma unroll
    for (int i = 0; i < 2; ++i)
      #pragma unroll
      for (int j = 0; j < 2; ++j) {
        f32x4 t = acc[i][j];
        t = __builtin_amdgcn_mfma_f32_16x16x32_bf16(af[i], bfh[j], t, 0, 0, 0);
        if constexpr (SB)
          t = __builtin_amdgcn_mfma_f32_16x16x32_bf16(af[i], bfl[j], t, 0, 0, 0);
        acc[i][j] = t;
      }
  }
  if constexpr (TRANS) __syncthreads();
  #pragma unroll
  for (int i = 0; i < 2; ++i) {
    const int row = m0 + wm + i * 16 + quad * 4;
    #pragma unroll
    for (int j = 0; j < 2; ++j) {
      const int col = n0 + wn + j * 16 + lm;
      const float bv = bias[col];
      #pragma unroll
      for (int r = 0; r < 4; ++r) {
        float x = acc[i][j][r] + bv;
        if (GELU) x = 0.5f * x * (1.0f + erff(x * 0.70710678118654752f));
        const size_t ri = (size_t)(row + r) * CC + col;
        if (RESID == 1) x += residf[ri];
        if (RESID == 2) x += b2f(residh[ri]) + b2f(residl[ri]);
        if constexpr (TRANS) {
          ttile[wm + i * 16 + quad * 4 + r][wn + j * 16 + lm] = x;
        } else {
          const size_t oi = (size_t)(row + r) * ldc + col;
          if (OUTMODE == 0) outf[oi] = x;
          else outh[oi] = f2bf(x);
        }
      }
    }
  }
  if constexpr (TRANS) {
    __syncthreads();
    const int bi = m0 >> 10, s0 = m0 & 1023;
    const int s = tid & 63;
    #pragma unroll
    for (int c0 = 0; c0 < 64; c0 += 4) {
      const int col = c0 + (tid >> 6);
      outf[(size_t)(bi * 512 + n0 + col) * 1024 + s0 + s] = ttile[s][col];
    }
  }
}

// ---------- flash attention: GLD_LDS K & V^T staging, exp2 softmax -----------
__global__ __launch_bounds__(256) void attn_mfma(
    const unsigned short* __restrict__ QKh, const unsigned short* __restrict__ QKl,
    const unsigned short* __restrict__ Vt, unsigned short* __restrict__ Oh) {
  __shared__ __align__(16) unsigned short Ksh[64 * 64], Ksl[64 * 64];
  __shared__ __align__(16) unsigned short Vts[64 * 64];
  __shared__ __align__(16) unsigned short Ps[4 * 16 * 88];
  const int q0 = blockIdx.x * 64, h = blockIdx.y, b = blockIdx.z;
  const int tid = threadIdx.x, w = tid >> 6, l = tid & 63, quad = l >> 4, lm = l & 15;
  const int LDQ = 2 * CC;
  const size_t qkbase = (size_t)b * SS * LDQ;
  const int srow8 = tid >> 3;
  const int sch8  = ((tid & 7) ^ (srow8 & 7)) * 8;
  const unsigned short* Vg = Vt + ((size_t)(b * 8 + h) * 64 + srow8) * 1024 + sch8;
  short8 qh[2], ql[2];
  {
    const size_t qo = qkbase + (size_t)(q0 + w * 16 + lm) * LDQ + h * 64 + quad * 8;
    qh[0] = *(const short8*)(QKh + qo);
    qh[1] = *(const short8*)(QKh + qo + 32);
    ql[0] = *(const short8*)(QKl + qo);
    ql[1] = *(const short8*)(QKl + qo + 32);
  }
  short8 bones;
  #pragma unroll
  for (int u = 0; u < 8; ++u) bones[u] = (lm == 0) ? (short)0x3F80 : (short)0;
  const f32x4 fzero = {0.f, 0.f, 0.f, 0.f};
  float mrow[4];
  f32x4 oacc[5];
  #pragma unroll
  for (int r = 0; r < 4; ++r) mrow[r] = -1e30f;
  #pragma unroll
  for (int j = 0; j < 5; ++j) oacc[j] = fzero;
  const float scale = 0.044194173824159216f * 1.4426950408889634f;
  unsigned short* Pw = Ps + w * (16 * 88);
  for (int kt = 0; kt < SS; kt += 64) {
    __syncthreads();
    {
      const unsigned short* kg  = QKh + qkbase + (size_t)(kt + srow8) * LDQ + CC + h * 64 + sch8;
      const unsigned short* kgl = QKl + qkbase + (size_t)(kt + srow8) * LDQ + CC + h * 64 + sch8;
      GLD_LDS(kg, Ksh + w * 512);
      GLD_LDS(kg + 32 * LDQ, Ksh + 2048 + w * 512);
      GLD_LDS(kgl, Ksl + w * 512);
      GLD_LDS(kgl + 32 * LDQ, Ksl + 2048 + w * 512);
      GLD_LDS(Vg + kt, Vts + w * 512);
      GLD_LDS(Vg + kt + 32 * 1024, Vts + 2048 + w * 512);
    }
    __syncthreads();
    f32x4 sc[4];
    #pragma unroll
    for (int j = 0; j < 4; ++j) sc[j] = fzero;
    #pragma unroll
    for (int st = 0; st < 2; ++st) {
      const int kc = ((st * 4 + quad) ^ (lm & 7)) * 8;
      #pragma unroll
      for (int j = 0; j < 4; ++j) {
        short8 kh = *(const short8*)(Ksh + (j * 16 + lm) * 64 + kc);
        short8 kl = *(const short8*)(Ksl + (j * 16 + lm) * 64 + kc);
        f32x4 t = sc[j];
        t = __builtin_amdgcn_mfma_f32_16x16x32_bf16(qh[st], kh, t, 0, 0, 0);
        t = __builtin_amdgcn_mfma_f32_16x16x32_bf16(qh[st], kl, t, 0, 0, 0);
        t = __builtin_amdgcn_mfma_f32_16x16x32_bf16(ql[st], kh, t, 0, 0, 0);
        sc[j] = t;
      }
    }
    #pragma unroll
    for (int j = 0; j < 4; ++j) sc[j] *= scale;
    #pragma unroll
    for (int r = 0; r < 4; ++r) {
      float mt = fmaxf(fmaxf(sc[0][r], sc[1][r]), fmaxf(sc[2][r], sc[3][r]));
      #pragma unroll
      for (int mask = 1; mask < 16; mask <<= 1) mt = fmaxf(mt, __shfl_xor(mt, mask, 64));
      const float mn = fmaxf(mrow[r], mt);
      const float alpha = exp2f(mrow[r] - mn);
      mrow[r] = mn;
      #pragma unroll
      for (int j = 0; j < 4; ++j) sc[j][r] = exp2f(sc[j][r] - mn);
      #pragma unroll
      for (int j = 0; j < 5; ++j) oacc[j][r] *= alpha;
    }
    #pragma unroll
    for (int r = 0; r < 4; ++r)
      #pragma unroll
      for (int j = 0; j < 4; ++j)
        Pw[(quad * 4 + r) * 88 + j * 16 + lm] = f2bf(sc[j][r]);
    #pragma unroll
    for (int st = 0; st < 2; ++st) {
      short8 ap = *(const short8*)(Pw + lm * 88 + st * 32 + quad * 8);
      const int kc = ((st * 4 + quad) ^ (lm & 7)) * 8;
      #pragma unroll
      for (int j = 0; j < 4; ++j) {
        short8 vv = *(const short8*)(Vts + (j * 16 + lm) * 64 + kc);
        oacc[j] = __builtin_amdgcn_mfma_f32_16x16x32_bf16(ap, vv, oacc[j], 0, 0, 0);
      }
      oacc[4] = __builtin_amdgcn_mfma_f32_16x16x32_bf16(ap, bones, oacc[4], 0, 0, 0);
    }
  }
  float inv[4];
  #pragma unroll
  for (int r = 0; r < 4; ++r) {
    const float lv = __shfl(oacc[4][r], l & 48, 64);
    inv[r] = 1.f / lv;
  }
  const size_t obase =
      (size_t)b * SS * CC + (size_t)(q0 + w * 16 + quad * 4) * CC + h * 64 + lm;
  #pragma unroll
  for (int j = 0; j < 4; ++j)
    #pragma unroll
    for (int r = 0; r < 4; ++r)
      Oh[obase + (size_t)r * CC + j * 16] = f2bf(oacc[j][r] * inv[r]);
}

extern "C" void kernel_launch(void* const* d_in, const int* in_sizes, int n_in,
                              void* d_out, int out_size, void* d_ws, size_t ws_size,
                              hipStream_t stream) {
  const float* x    = (const float*)d_in[0];
  const float* K_W  = (const float*)d_in[2];
  const float* K_b  = (const float*)d_in[3];
  const float* Q_W  = (const float*)d_in[4];
  const float* Q_b  = (const float*)d_in[5];
  const float* V_W  = (const float*)d_in[6];
  const float* V_b  = (const float*)d_in[7];
  const float* O_W  = (const float*)d_in[8];
  const float* O_b  = (const float*)d_in[9];
  const float* ln1g = (const float*)d_in[10];
  const float* ln1b = (const float*)d_in[11];
  const float* ln2g = (const float*)d_in[12];
  const float* ln2b = (const float*)d_in[13];
  const float* W1   = (const float*)d_in[14];
  const float* b1   = (const float*)d_in[15];
  const float* W2   = (const float*)d_in[16];
  const float* b2   = (const float*)d_in[17];
  float* out = (float*)d_out;

  unsigned char* ws = (unsigned char*)d_ws;
  const size_t MB = 1u << 20;
  unsigned short* qkh   = (unsigned short*)(ws);             // (B,S,1024) 16MB
  unsigned short* qkl   = (unsigned short*)(ws + 16 * MB);   // 16MB
  unsigned short* vt    = (unsigned short*)(ws + 32 * MB);   // (B,NH,HD,S) 8MB
  unsigned short* ln1h  = (unsigned short*)(ws + 40 * MB);   // 8MB
  unsigned short* ln1l  = (unsigned short*)(ws + 48 * MB);   // 8MB
  unsigned short* xsh   = (unsigned short*)(ws + 56 * MB);   // 8MB (residual hi)
  unsigned short* xsl   = (unsigned short*)(ws + 64 * MB);   // 8MB (residual lo)
  unsigned short* oh    = ln1h;                              // reuse after QKV GEMM
  float* out1           = (float*)(ws + 72 * MB);            // 16MB fp32 residual
  unsigned short* ln2h  = qkh;                               // reuse (qk dead post-attn)
  unsigned short* geluh = (unsigned short*)(ws + 8 * MB);    // reuse qkh 2nd half
  unsigned short* BtAll = (unsigned short*)(ws + 88 * MB);   // [QKh 1024 | Vh 512] x 512
  unsigned short* BtQKh = BtAll;
  unsigned short* BtVh  = BtAll + 1024 * 512;
  unsigned short* BtQKl = BtVh + 512 * 512;
  unsigned short* BtOh  = BtQKl + 1024 * 512;
  unsigned short* BtOl  = BtOh + 512 * 512;
  unsigned short* BtW1h = BtOl + 512 * 512;
  unsigned short* BtW2h = BtW1h + 512 * 512;
  float* qkvb           = (float*)(BtW2h + 512 * 512);
  float2* mustd         = (float2*)(ws + 96 * MB);           // 8192 x 8B

  dim3 tb32(32, 8);
  convert_weights<<<dim3(16, 2, 48), tb32, 0, stream>>>(
      Q_W, K_W, V_W, O_W, W1, W2, Q_b, K_b, V_b,
      BtQKh, BtQKl, BtVh, BtOh, BtOl, BtW1h, BtW2h, qkvb);
  // LN1: parallel stats then transpose-style apply
  ln1_stats<<<dim3(SS / 64, BB), 256, 0, stream>>>(x, mustd);
  ln1_apply<<<dim3(SS / 32, CC / 32, BB), tb32, 0, stream>>>(
      x, mustd, ln1g, ln1b, ln1h, ln1l, xsh, xsl);
  gemm_qkv<<<dim3(12, 64), 256, 0, stream>>>(
      ln1h, ln1l, BtAll, BtQKl, qkvb, qkh, qkl, vt);
  attn_mfma<<<dim3(SS / 64, NHH, BB), 256, 0, stream>>>(qkh, qkl, vt, oh);
  gemm64<1, 0, 0, 2, 0><<<dim3(8, 128), 256, 0, stream>>>(
      oh, BtOh, BtOl, O_b, nullptr, xsh, xsl, nullptr, out1, CC);
  ln_bf16_k<<<BB * SS, 256, 0, stream>>>(out1, ln2g, ln2b, ln2h);
  gemm64<0, 1, 1, 0, 0><<<dim3(8, 128), 256, 0, stream>>>(
      ln2h, BtW1h, nullptr, b1, nullptr, nullptr, nullptr, geluh, nullptr, CC);
  gemm64<0, 0, 0, 1, 1><<<dim3(8, 128), 256, 0, stream>>>(
      geluh, BtW2h, nullptr, b2, out1, nullptr, nullptr, nullptr, out, CC);
}

// Round 10
// 291.683 us; speedup vs baseline: 1.1641x; 1.0543x over previous
//
#include <hip/hip_runtime.h>
#include <math.h>

#define BB 8
#define CC 512
#define SS 1024
#define NHH 8
#define HDD 64
#define KD 512

typedef __attribute__((ext_vector_type(8))) short short8;
typedef __attribute__((ext_vector_type(4))) float f32x4;
typedef __attribute__((ext_vector_type(4))) unsigned short ushort4v;

__device__ __forceinline__ unsigned short f2bf(float x) {
  union { float f; unsigned int u; } c; c.f = x;
  unsigned int r = (c.u + 0x7FFFu + ((c.u >> 16) & 1u)) >> 16;
  return (unsigned short)r;
}
__device__ __forceinline__ float b2f(unsigned short h) {
  union { unsigned int u; float f; } c; c.u = ((unsigned int)h) << 16; return c.f;
}

#define GLD_LDS(gp, lp) __builtin_amdgcn_global_load_lds( \
    (const __attribute__((address_space(1))) void*)(gp),  \
    (__attribute__((address_space(3))) void*)(lp), 16, 0, 0)

// ---------- block-wide sum over 256 threads (4 waves) ----------
__device__ __forceinline__ float block_reduce_sum(float v) {
  __shared__ float sm[4];
  #pragma unroll
  for (int o = 32; o > 0; o >>= 1) v += __shfl_down(v, o, 64);
  if ((threadIdx.x & 63) == 0) sm[threadIdx.x >> 6] = v;
  __syncthreads();
  float r = (sm[0] + sm[1]) + (sm[2] + sm[3]);
  __syncthreads();
  return r;
}

// ---------- LN1 stats: x (B,C,S) -> (mu, rstd) per (b,s) ---------------------
__global__ __launch_bounds__(256) void ln1_stats(const float* __restrict__ x,
                                                 float2* __restrict__ mustd) {
  const int b = blockIdx.y, s0 = blockIdx.x * 64;
  const int sl = threadIdx.x & 63, cg = threadIdx.x >> 6;
  const float* xp = x + (size_t)b * CC * SS + s0 + sl;
  float ps = 0.f, pq = 0.f;
  #pragma unroll 8
  for (int i = 0; i < 128; ++i) {
    const float v = xp[(size_t)(cg * 128 + i) * SS];
    ps += v; pq += v * v;
  }
  __shared__ float sred[2][4][64];
  sred[0][cg][sl] = ps; sred[1][cg][sl] = pq;
  __syncthreads();
  if (cg == 0) {
    const float s = (sred[0][0][sl] + sred[0][1][sl]) + (sred[0][2][sl] + sred[0][3][sl]);
    const float q = (sred[1][0][sl] + sred[1][1][sl]) + (sred[1][2][sl] + sred[1][3][sl]);
    const float mu = s * (1.0f / CC);
    const float rs = rsqrtf(q * (1.0f / CC) - mu * mu + 1e-5f);
    mustd[b * SS + s0 + sl] = make_float2(mu, rs);
  }
}

// ---------- LN1 apply + transpose: -> ln1 h/l + xs h/l (B,S,C) ---------------
__global__ __launch_bounds__(256) void ln1_apply(
    const float* __restrict__ x, const float2* __restrict__ mustd,
    const float* __restrict__ g, const float* __restrict__ be,
    unsigned short* __restrict__ yh, unsigned short* __restrict__ yl,
    unsigned short* __restrict__ xh, unsigned short* __restrict__ xl) {
  __shared__ float tile[32][33];
  const int b = blockIdx.z, c0 = blockIdx.y * 32, s0 = blockIdx.x * 32;
  const int tx = threadIdx.x, ty = threadIdx.y;
  const float* xb = x + ((size_t)b * CC + c0) * SS + s0;
  #pragma unroll
  for (int i = ty; i < 32; i += 8)
    tile[i][tx] = xb[(size_t)i * SS + tx];
  __syncthreads();
  const float gc = g[c0 + tx], bc = be[c0 + tx];
  #pragma unroll
  for (int i = ty; i < 32; i += 8) {
    const float2 ms = mustd[b * SS + s0 + i];
    const float v = tile[tx][i];
    const float y = (v - ms.x) * ms.y * gc + bc;
    const size_t oi = ((size_t)b * SS + s0 + i) * CC + c0 + tx;
    const unsigned short hy = f2bf(y);
    yh[oi] = hy; yl[oi] = f2bf(y - b2f(hy));
    const unsigned short hx = f2bf(v);
    xh[oi] = hx; xl[oi] = f2bf(v - b2f(hx));
  }
}

// ---------- LayerNorm (C=512) contiguous rows -> bf16 hi ---------------------
__global__ __launch_bounds__(256) void ln_bf16_k(const float* __restrict__ in,
                                                 const float* __restrict__ g,
                                                 const float* __restrict__ be,
                                                 unsigned short* __restrict__ outh) {
  size_t row = blockIdx.x;
  const float* r = in + row * CC;
  int t = threadIdx.x;
  float v0 = r[t], v1 = r[t + 256];
  float s = block_reduce_sum(v0 + v1);
  float mu = s * (1.0f / CC);
  float d0 = v0 - mu, d1 = v1 - mu;
  float vs = block_reduce_sum(d0 * d0 + d1 * d1);
  float rstd = rsqrtf(vs * (1.0f / CC) + 1e-5f);
  outh[row * CC + t]       = f2bf(d0 * rstd * g[t] + be[t]);
  outh[row * CC + t + 256] = f2bf(d1 * rstd * g[t + 256] + be[t + 256]);
}

// ---------- weight convert: fp32 -> bf16 hi/lo B^T (N,K) ---------------------
// Q_W / Q_b are pre-scaled by 1/sqrt(512)*log2(e): scores exit QK^T pre-scaled.
__global__ __launch_bounds__(256) void convert_weights(
    const float* __restrict__ QW, const float* __restrict__ KW,
    const float* __restrict__ VW, const float* __restrict__ OW,
    const float* __restrict__ W1, const float* __restrict__ W2,
    const float* __restrict__ Qb, const float* __restrict__ Kb,
    const float* __restrict__ Vb,
    unsigned short* __restrict__ BtQKh, unsigned short* __restrict__ BtQKl,
    unsigned short* __restrict__ BtVh,
    unsigned short* __restrict__ BtOh, unsigned short* __restrict__ BtOl,
    unsigned short* __restrict__ BtW1h, unsigned short* __restrict__ BtW2h,
    float* __restrict__ qkvb) {
  const float SCL = 0.044194173824159216f * 1.4426950408889634f;
  __shared__ float tile[32][33];
  const int p = blockIdx.z, wsel = p >> 3, sub = p & 7;
  const int k0 = blockIdx.x * 32, d0 = blockIdx.y * 32;
  const int tx = threadIdx.x, ty = threadIdx.y;
  const float* w; int rs; unsigned short *dh, *dl; int nbase; float mul = 1.0f;
  switch (wsel) {
    case 0:  w = QW + sub * 32768; rs = 64;  dh = BtQKh; dl = BtQKl;  nbase = sub * 64; mul = SCL; break;
    case 1:  w = KW + sub * 32768; rs = 64;  dh = BtQKh; dl = BtQKl;  nbase = 512 + sub * 64;  break;
    case 2:  w = VW + sub * 32768; rs = 64;  dh = BtVh;  dl = nullptr; nbase = sub * 64;       break;
    case 3:  w = OW + sub * 64;    rs = 512; dh = BtOh;  dl = BtOl;   nbase = sub * 64;        break;
    case 4:  w = W1 + sub * 64;    rs = 512; dh = BtW1h; dl = nullptr; nbase = sub * 64;       break;
    default: w = W2 + sub * 64;    rs = 512; dh = BtW2h; dl = nullptr; nbase = sub * 64;       break;
  }
  for (int i = ty; i < 32; i += 8)
    tile[i][tx] = w[(size_t)(k0 + i) * rs + d0 + tx];
  __syncthreads();
  for (int i = ty; i < 32; i += 8) {
    float f = tile[tx][i] * mul;
    unsigned short h = f2bf(f);
    size_t idx = (size_t)(nbase + d0 + i) * KD + k0 + tx;
    dh[idx] = h;
    if (dl) dl[idx] = f2bf(f - b2f(h));
  }
  if (p == 0 && blockIdx.x == 0 && blockIdx.y == 0) {
    int t = ty * 32 + tx;
    for (int i = t; i < 1536; i += 256)
      qkvb[i] = i < 512 ? Qb[i] * SCL : (i < 1024 ? Kb[i - 512] : Vb[i - 1024]);
  }
}

// ---------- fused QKV projection GEMM, 128x128 tiles, xor-swizzled LDS -------
__global__ __launch_bounds__(256) void gemm_qkv(
    const unsigned short* __restrict__ Ah, const unsigned short* __restrict__ Al,
    const unsigned short* __restrict__ Bth, const unsigned short* __restrict__ Btl,
    const float* __restrict__ bias,
    unsigned short* __restrict__ qkh, unsigned short* __restrict__ qkl,
    unsigned short* __restrict__ vt) {
  __shared__ __align__(16) unsigned short smem[4 * 128 * 32];
  unsigned short* As = smem;
  unsigned short* Bs = smem + 2 * 128 * 32;
  const int tid = threadIdx.x;
  const int w = tid >> 6, l = tid & 63, quad = l >> 4, lm = l & 15;
  const int n0 = blockIdx.x * 128, m0 = blockIdx.y * 128;
  const bool splitB = n0 < 1024;
  const int wm = (w >> 1) * 64, wn = (w & 1) * 64;
  const int srow = tid >> 2;
  const int sch = (((tid & 3) ^ (srow & 3)) * 8);
  const unsigned short* Agh = Ah + (size_t)(m0 + srow) * KD + sch;
  const unsigned short* Agl = Al + (size_t)(m0 + srow) * KD + sch;
  const unsigned short* Bgh = Bth + (size_t)(n0 + srow) * KD + sch;
  const unsigned short* Bgl = Btl + (size_t)(n0 + srow) * KD + sch;
  unsigned short* Aswh = As + w * 512;
  unsigned short* Aswl = As + 4096 + w * 512;
  unsigned short* Bswh = Bs + w * 512;
  unsigned short* Bswl = Bs + 4096 + w * 512;
  const int rch = ((quad ^ (lm & 3)) * 8);
  const f32x4 fzero = {0.f, 0.f, 0.f, 0.f};
  f32x4 acc[4][4];
  #pragma unroll
  for (int i = 0; i < 4; ++i)
    #pragma unroll
    for (int j = 0; j < 4; ++j) acc[i][j] = fzero;
  for (int k0 = 0; k0 < KD; k0 += 32) {
    __syncthreads();
    GLD_LDS(Agh + k0, Aswh);
    GLD_LDS(Agh + k0 + 64 * KD, Aswh + 2048);
    GLD_LDS(Agl + k0, Aswl);
    GLD_LDS(Agl + k0 + 64 * KD, Aswl + 2048);
    GLD_LDS(Bgh + k0, Bswh);
    GLD_LDS(Bgh + k0 + 64 * KD, Bswh + 2048);
    if (splitB) {
      GLD_LDS(Bgl + k0, Bswl);
      GLD_LDS(Bgl + k0 + 64 * KD, Bswl + 2048);
    }
    __syncthreads();
    short8 afh[4], afl[4], bfh[4], bfl[4];
    #pragma unroll
    for (int i = 0; i < 4; ++i) {
      afh[i] = *(const short8*)(As + (wm + i * 16 + lm) * 32 + rch);
      afl[i] = *(const short8*)(As + 4096 + (wm + i * 16 + lm) * 32 + rch);
    }
    #pragma unroll
    for (int j = 0; j < 4; ++j)
      bfh[j] = *(const short8*)(Bs + (wn + j * 16 + lm) * 32 + rch);
    if (splitB) {
      #pragma unroll
      for (int j = 0; j < 4; ++j)
        bfl[j] = *(const short8*)(Bs + 4096 + (wn + j * 16 + lm) * 32 + rch);
      #pragma unroll
      for (int i = 0; i < 4; ++i)
        #pragma unroll
        for (int j = 0; j < 4; ++j) {
          f32x4 t = acc[i][j];
          t = __builtin_amdgcn_mfma_f32_16x16x32_bf16(afh[i], bfh[j], t, 0, 0, 0);
          t = __builtin_amdgcn_mfma_f32_16x16x32_bf16(afh[i], bfl[j], t, 0, 0, 0);
          t = __builtin_amdgcn_mfma_f32_16x16x32_bf16(afl[i], bfh[j], t, 0, 0, 0);
          acc[i][j] = t;
        }
    } else {
      #pragma unroll
      for (int i = 0; i < 4; ++i)
        #pragma unroll
        for (int j = 0; j < 4; ++j)
          acc[i][j] = __builtin_amdgcn_mfma_f32_16x16x32_bf16(afh[i], bfh[j], acc[i][j], 0, 0, 0);
    }
  }
  if (splitB) {
    #pragma unroll
    for (int i = 0; i < 4; ++i) {
      const int row = m0 + wm + i * 16 + quad * 4;
      #pragma unroll
      for (int j = 0; j < 4; ++j) {
        const int ncol = n0 + wn + j * 16 + lm;
        const float bv = bias[ncol];
        #pragma unroll
        for (int r = 0; r < 4; ++r) {
          const float xv = acc[i][j][r] + bv;
          const size_t oi = (size_t)(row + r) * 1024 + ncol;
          unsigned short h = f2bf(xv);
          qkh[oi] = h;
          qkl[oi] = f2bf(xv - b2f(h));
        }
      }
    }
  } else {
    __syncthreads();
    #pragma unroll
    for (int i = 0; i < 4; ++i) {
      const int mlb = wm + i * 16 + quad * 4;
      #pragma unroll
      for (int j = 0; j < 4; ++j) {
        const int nl = wn + j * 16 + lm;
        const float bv = bias[n0 + nl];
        ushort4v pk;
        #pragma unroll
        for (int r = 0; r < 4; ++r) pk[r] = f2bf(acc[i][j][r] + bv);
        const int chunk = ((mlb >> 3) ^ (nl & 15));
        *(ushort4v*)(smem + nl * 128 + chunk * 8 + (mlb & 7)) = pk;
      }
    }
    __syncthreads();
    const int tn = tid >> 4, tc = tid & 15;
    const int bb2 = m0 >> 10, sbase = m0 & 1023;
    #pragma unroll
    for (int pass = 0; pass < 8; ++pass) {
      const int nl = pass * 16 + tn;
      const int hh = (n0 - 1024 + nl) >> 6, dd = nl & 63;
      short8 v8 = *(const short8*)(smem + nl * 128 + ((tc ^ (nl & 15)) * 8));
      *(short8*)(vt + ((size_t)(bb2 * 8 + hh) * 64 + dd) * 1024 + sbase + tc * 8) = v8;
    }
  }
}

// ---------- 64x64-tile GEMM, BK=64, GLD staging, xor-swizzled ----------------
// RESID: 0 none, 1 fp32 ptr, 2 bf16 h+l pair. TRANS: write (B,C,S) via LDS.
template<int SB, int GELU, int OUTMODE, int RESID, int TRANS>
__global__ __launch_bounds__(256) void gemm64(
    const unsigned short* __restrict__ Ah,
    const unsigned short* __restrict__ Bh, const unsigned short* __restrict__ Bl,
    const float* __restrict__ bias, const float* __restrict__ residf,
    const unsigned short* __restrict__ residh, const unsigned short* __restrict__ residl,
    unsigned short* __restrict__ outh, float* __restrict__ outf, int ldc) {
  constexpr int STAGE = (SB ? 3 : 2) * 8192;
  constexpr int TSIZE = TRANS ? 64 * 65 * 4 : 0;
  __shared__ __align__(16) unsigned char smem[STAGE > TSIZE ? STAGE : TSIZE];
  unsigned short* As  = (unsigned short*)smem;            // [64][64]
  unsigned short* Bs  = (unsigned short*)(smem + 8192);
  unsigned short* Bls = (unsigned short*)(smem + 16384);
  float (*ttile)[65]  = (float(*)[65])smem;
  const int tid = threadIdx.x;
  const int w = tid >> 6, l = tid & 63, quad = l >> 4, lm = l & 15;
  const int n0 = blockIdx.x * 64, m0 = blockIdx.y * 64;
  const int wm = (w >> 1) * 32, wn = (w & 1) * 32;
  const int srow8 = tid >> 3;                       // 0..31
  const int sch8  = ((tid & 7) ^ (srow8 & 7)) * 8;  // xor-swizzled 16B chunk
  const unsigned short* Ag  = Ah + (size_t)(m0 + srow8) * KD + sch8;
  const unsigned short* Bg  = Bh + (size_t)(n0 + srow8) * KD + sch8;
  const unsigned short* Bgl = SB ? Bl + (size_t)(n0 + srow8) * KD + sch8 : nullptr;
  const f32x4 fzero = {0.f, 0.f, 0.f, 0.f};
  f32x4 acc[2][2];
  #pragma unroll
  for (int i = 0; i < 2; ++i)
    #pragma unroll
    for (int j = 0; j < 2; ++j) acc[i][j] = fzero;
  for (int k0 = 0; k0 < KD; k0 += 64) {
    __syncthreads();
    GLD_LDS(Ag + k0, As + w * 512);
    GLD_LDS(Ag + k0 + 32 * KD, As + 2048 + w * 512);
    GLD_LDS(Bg + k0, Bs + w * 512);
    GLD_LDS(Bg + k0 + 32 * KD, Bs + 2048 + w * 512);
    if constexpr (SB) {
      GLD_LDS(Bgl + k0, Bls + w * 512);
      GLD_LDS(Bgl + k0 + 32 * KD, Bls + 2048 + w * 512);
    }
    __syncthreads();
    #pragma unroll
    for (int ks = 0; ks < 2; ++ks) {
      const int kc = ((ks * 4 + quad) ^ (lm & 7)) * 8;
      short8 af[2], bfh[2], bfl[2];
      #pragma unroll
      for (int i = 0; i < 2; ++i)
        af[i] = *(const short8*)(As + (wm + i * 16 + lm) * 64 + kc);
      #pragma unroll
      for (int j = 0; j < 2; ++j)
        bfh[j] = *(const short8*)(Bs + (wn + j * 16 + lm) * 64 + kc);
      if constexpr (SB) {
        #pragma unroll
        for (int j = 0; j < 2; ++j)
          bfl[j] = *(const short8*)(Bls + (wn + j * 16 + lm) * 64 + kc);
      }
      #pragma unroll
      for (int i = 0; i < 2; ++i)
        #pragma unroll
        for (int j = 0; j < 2; ++j) {
          f32x4 t = acc[i][j];
          t = __builtin_amdgcn_mfma_f32_16x16x32_bf16(af[i], bfh[j], t, 0, 0, 0);
          if constexpr (SB)
            t = __builtin_amdgcn_mfma_f32_16x16x32_bf16(af[i], bfl[j], t, 0, 0, 0);
          acc[i][j] = t;
        }
    }
  }
  if constexpr (TRANS) __syncthreads();  // staging reads done; smem becomes ttile
  #pragma unroll
  for (int i = 0; i < 2; ++i) {
    const int row = m0 + wm + i * 16 + quad * 4;
    #pragma unroll
    for (int j = 0; j < 2; ++j) {
      const int col = n0 + wn + j * 16 + lm;
      const float bv = bias[col];
      #pragma unroll
      for (int r = 0; r < 4; ++r) {
        float x = acc[i][j][r] + bv;
        if (GELU) x = 0.5f * x * (1.0f + erff(x * 0.70710678118654752f));
        const size_t ri = (size_t)(row + r) * CC + col;
        if (RESID == 1) x += residf[ri];
        if (RESID == 2) x += b2f(residh[ri]) + b2f(residl[ri]);
        if constexpr (TRANS) {
          ttile[wm + i * 16 + quad * 4 + r][wn + j * 16 + lm] = x;
        } else {
          const size_t oi = (size_t)(row + r) * ldc + col;
          if (OUTMODE == 0) outf[oi] = x;
          else outh[oi] = f2bf(x);
        }
      }
    }
  }
  if constexpr (TRANS) {
    __syncthreads();
    const int bi = m0 >> 10, s0 = m0 & 1023;
    const int s = tid & 63;
    #pragma unroll
    for (int c0 = 0; c0 < 64; c0 += 4) {
      const int col = c0 + (tid >> 6);
      outf[(size_t)(bi * 512 + n0 + col) * 1024 + s0 + s] = ttile[s][col];
    }
  }
}

// ---------- flash attention: pre-scaled Q, GLD staging, truncated P ----------
__global__ __launch_bounds__(256) void attn_mfma(
    const unsigned short* __restrict__ QKh, const unsigned short* __restrict__ QKl,
    const unsigned short* __restrict__ Vt, unsigned short* __restrict__ Oh) {
  __shared__ __align__(16) unsigned short Ksh[64 * 64], Ksl[64 * 64];
  __shared__ __align__(16) unsigned short Vts[64 * 64];
  __shared__ __align__(16) unsigned short Ps[4 * 16 * 88];
  const int q0 = blockIdx.x * 64, h = blockIdx.y, b = blockIdx.z;
  const int tid = threadIdx.x, w = tid >> 6, l = tid & 63, quad = l >> 4, lm = l & 15;
  const int LDQ = 2 * CC;
  const size_t qkbase = (size_t)b * SS * LDQ;
  const int srow8 = tid >> 3;
  const int sch8  = ((tid & 7) ^ (srow8 & 7)) * 8;
  const unsigned short* Vg = Vt + ((size_t)(b * 8 + h) * 64 + srow8) * 1024 + sch8;
  short8 qh[2], ql[2];
  {
    const size_t qo = qkbase + (size_t)(q0 + w * 16 + lm) * LDQ + h * 64 + quad * 8;
    qh[0] = *(const short8*)(QKh + qo);
    qh[1] = *(const short8*)(QKh + qo + 32);
    ql[0] = *(const short8*)(QKl + qo);
    ql[1] = *(const short8*)(QKl + qo + 32);
  }
  short8 bones;
  #pragma unroll
  for (int u = 0; u < 8; ++u) bones[u] = (lm == 0) ? (short)0x3F80 : (short)0;
  const f32x4 fzero = {0.f, 0.f, 0.f, 0.f};
  float mrow[4];
  f32x4 oacc[5];
  #pragma unroll
  for (int r = 0; r < 4; ++r) mrow[r] = -1e30f;
  #pragma unroll
  for (int j = 0; j < 5; ++j) oacc[j] = fzero;
  unsigned short* Pw = Ps + w * (16 * 88);
  for (int kt = 0; kt < SS; kt += 64) {
    __syncthreads();
    {
      const unsigned short* kg  = QKh + qkbase + (size_t)(kt + srow8) * LDQ + CC + h * 64 + sch8;
      const unsigned short* kgl = QKl + qkbase + (size_t)(kt + srow8) * LDQ + CC + h * 64 + sch8;
      GLD_LDS(kg, Ksh + w * 512);
      GLD_LDS(kg + 32 * LDQ, Ksh + 2048 + w * 512);
      GLD_LDS(kgl, Ksl + w * 512);
      GLD_LDS(kgl + 32 * LDQ, Ksl + 2048 + w * 512);
      GLD_LDS(Vg + kt, Vts + w * 512);
      GLD_LDS(Vg + kt + 32 * 1024, Vts + 2048 + w * 512);
    }
    __syncthreads();
    f32x4 sc[4];
    #pragma unroll
    for (int j = 0; j < 4; ++j) sc[j] = fzero;
    #pragma unroll
    for (int st = 0; st < 2; ++st) {
      const int kc = ((st * 4 + quad) ^ (lm & 7)) * 8;
      #pragma unroll
      for (int j = 0; j < 4; ++j) {
        short8 kh = *(const short8*)(Ksh + (j * 16 + lm) * 64 + kc);
        short8 kl = *(const short8*)(Ksl + (j * 16 + lm) * 64 + kc);
        f32x4 t = sc[j];
        t = __builtin_amdgcn_mfma_f32_16x16x32_bf16(qh[st], kh, t, 0, 0, 0);
        t = __builtin_amdgcn_mfma_f32_16x16x32_bf16(qh[st], kl, t, 0, 0, 0);
        t = __builtin_amdgcn_mfma_f32_16x16x32_bf16(ql[st], kh, t, 0, 0, 0);
        sc[j] = t;
      }
    }
    // scores are pre-scaled (scale*log2e folded into Q weights/bias)
    #pragma unroll
    for (int r = 0; r < 4; ++r) {
      float mt = fmaxf(fmaxf(sc[0][r], sc[1][r]), fmaxf(sc[2][r], sc[3][r]));
      #pragma unroll
      for (int mask = 1; mask < 16; mask <<= 1) mt = fmaxf(mt, __shfl_xor(mt, mask, 64));
      const float mn = fmaxf(mrow[r], mt);
      const float alpha = exp2f(mrow[r] - mn);
      mrow[r] = mn;
      #pragma unroll
      for (int j = 0; j < 4; ++j) sc[j][r] = exp2f(sc[j][r] - mn);
      #pragma unroll
      for (int j = 0; j < 5; ++j) oacc[j][r] *= alpha;
    }
    // P -> per-wave LDS, truncated bf16 (self-consistent with ones-column sum)
    #pragma unroll
    for (int r = 0; r < 4; ++r)
      #pragma unroll
      for (int j = 0; j < 4; ++j) {
        union { float f; unsigned int u; } pc; pc.f = sc[j][r];
        Pw[(quad * 4 + r) * 88 + j * 16 + lm] = (unsigned short)(pc.u >> 16);
      }
    #pragma unroll
    for (int st = 0; st < 2; ++st) {
      short8 ap = *(const short8*)(Pw + lm * 88 + st * 32 + quad * 8);
      const int kc = ((st * 4 + quad) ^ (lm & 7)) * 8;
      #pragma unroll
      for (int j = 0; j < 4; ++j) {
        short8 vv = *(const short8*)(Vts + (j * 16 + lm) * 64 + kc);
        oacc[j] = __builtin_amdgcn_mfma_f32_16x16x32_bf16(ap, vv, oacc[j], 0, 0, 0);
      }
      oacc[4] = __builtin_amdgcn_mfma_f32_16x16x32_bf16(ap, bones, oacc[4], 0, 0, 0);
    }
  }
  float inv[4];
  #pragma unroll
  for (int r = 0; r < 4; ++r) {
    const float lv = __shfl(oacc[4][r], l & 48, 64);
    inv[r] = 1.f / lv;
  }
  const size_t obase =
      (size_t)b * SS * CC + (size_t)(q0 + w * 16 + quad * 4) * CC + h * 64 + lm;
  #pragma unroll
  for (int j = 0; j < 4; ++j)
    #pragma unroll
    for (int r = 0; r < 4; ++r)
      Oh[obase + (size_t)r * CC + j * 16] = f2bf(oacc[j][r] * inv[r]);
}

extern "C" void kernel_launch(void* const* d_in, const int* in_sizes, int n_in,
                              void* d_out, int out_size, void* d_ws, size_t ws_size,
                              hipStream_t stream) {
  const float* x    = (const float*)d_in[0];
  const float* K_W  = (const float*)d_in[2];
  const float* K_b  = (const float*)d_in[3];
  const float* Q_W  = (const float*)d_in[4];
  const float* Q_b  = (const float*)d_in[5];
  const float* V_W  = (const float*)d_in[6];
  const float* V_b  = (const float*)d_in[7];
  const float* O_W  = (const float*)d_in[8];
  const float* O_b  = (const float*)d_in[9];
  const float* ln1g = (const float*)d_in[10];
  const float* ln1b = (const float*)d_in[11];
  const float* ln2g = (const float*)d_in[12];
  const float* ln2b = (const float*)d_in[13];
  const float* W1   = (const float*)d_in[14];
  const float* b1   = (const float*)d_in[15];
  const float* W2   = (const float*)d_in[16];
  const float* b2   = (const float*)d_in[17];
  float* out = (float*)d_out;

  unsigned char* ws = (unsigned char*)d_ws;
  const size_t MB = 1u << 20;
  unsigned short* qkh   = (unsigned short*)(ws);             // (B,S,1024) 16MB
  unsigned short* qkl   = (unsigned short*)(ws + 16 * MB);   // 16MB
  unsigned short* vt    = (unsigned short*)(ws + 32 * MB);   // (B,NH,HD,S) 8MB
  unsigned short* ln1h  = (unsigned short*)(ws + 40 * MB);   // 8MB
  unsigned short* ln1l  = (unsigned short*)(ws + 48 * MB);   // 8MB
  unsigned short* xsh   = (unsigned short*)(ws + 56 * MB);   // 8MB
  unsigned short* xsl   = (unsigned short*)(ws + 64 * MB);   // 8MB
  unsigned short* oh    = ln1h;
  float* out1           = (float*)(ws + 72 * MB);            // 16MB
  unsigned short* ln2h  = qkh;
  unsigned short* geluh = (unsigned short*)(ws + 8 * MB);
  unsigned short* BtAll = (unsigned short*)(ws + 88 * MB);
  unsigned short* BtQKh = BtAll;
  unsigned short* BtVh  = BtAll + 1024 * 512;
  unsigned short* BtQKl = BtVh + 512 * 512;
  unsigned short* BtOh  = BtQKl + 1024 * 512;
  unsigned short* BtOl  = BtOh + 512 * 512;
  unsigned short* BtW1h = BtOl + 512 * 512;
  unsigned short* BtW2h = BtW1h + 512 * 512;
  float* qkvb           = (float*)(BtW2h + 512 * 512);
  float2* mustd         = (float2*)(ws + 96 * MB);

  dim3 tb32(32, 8);
  convert_weights<<<dim3(16, 2, 48), tb32, 0, stream>>>(
      Q_W, K_W, V_W, O_W, W1, W2, Q_b, K_b, V_b,
      BtQKh, BtQKl, BtVh, BtOh, BtOl, BtW1h, BtW2h, qkvb);
  ln1_stats<<<dim3(SS / 64, BB), 256, 0, stream>>>(x, mustd);
  ln1_apply<<<dim3(SS / 32, CC / 32, BB), tb32, 0, stream>>>(
      x, mustd, ln1g, ln1b, ln1h, ln1l, xsh, xsl);
  gemm_qkv<<<dim3(12, 64), 256, 0, stream>>>(
      ln1h, ln1l, BtAll, BtQKl, qkvb, qkh, qkl, vt);
  attn_mfma<<<dim3(SS / 64, NHH, BB), 256, 0, stream>>>(qkh, qkl, vt, oh);
  gemm64<1, 0, 0, 2, 0><<<dim3(8, 128), 256, 0, stream>>>(
      oh, BtOh, BtOl, O_b, nullptr, xsh, xsl, nullptr, out1, CC);
  ln_bf16_k<<<BB * SS, 256, 0, stream>>>(out1, ln2g, ln2b, ln2h);
  gemm64<0, 1, 1, 0, 0><<<dim3(8, 128), 256, 0, stream>>>(
      ln2h, BtW1h, nullptr, b1, nullptr, nullptr, nullptr, geluh, nullptr, CC);
  gemm64<0, 0, 0, 1, 1><<<dim3(8, 128), 256, 0, stream>>>(
      geluh, BtW2h, nullptr, b2, out1, nullptr, nullptr, nullptr, out, CC);
}

// Round 11
// 285.453 us; speedup vs baseline: 1.1895x; 1.0218x over previous
//
#include <hip/hip_runtime.h>
#include <math.h>

#define BB 8
#define CC 512
#define SS 1024
#define NHH 8
#define HDD 64
#define KD 512

typedef __attribute__((ext_vector_type(8))) short short8;
typedef __attribute__((ext_vector_type(4))) float f32x4;
typedef __attribute__((ext_vector_type(4))) unsigned short ushort4v;

__device__ __forceinline__ unsigned short f2bf(float x) {
  union { float f; unsigned int u; } c; c.f = x;
  unsigned int r = (c.u + 0x7FFFu + ((c.u >> 16) & 1u)) >> 16;
  return (unsigned short)r;
}
__device__ __forceinline__ float b2f(unsigned short h) {
  union { unsigned int u; float f; } c; c.u = ((unsigned int)h) << 16; return c.f;
}

#define GLD_LDS(gp, lp) __builtin_amdgcn_global_load_lds( \
    (const __attribute__((address_space(1))) void*)(gp),  \
    (__attribute__((address_space(3))) void*)(lp), 16, 0, 0)

// ---------- block-wide sum over 256 threads (4 waves) ----------
__device__ __forceinline__ float block_reduce_sum(float v) {
  __shared__ float sm[4];
  #pragma unroll
  for (int o = 32; o > 0; o >>= 1) v += __shfl_down(v, o, 64);
  if ((threadIdx.x & 63) == 0) sm[threadIdx.x >> 6] = v;
  __syncthreads();
  float r = (sm[0] + sm[1]) + (sm[2] + sm[3]);
  __syncthreads();
  return r;
}

// ---------- LN1 stats: x (B,C,S) -> (mu, rstd) per (b,s) ---------------------
__global__ __launch_bounds__(256) void ln1_stats(const float* __restrict__ x,
                                                 float2* __restrict__ mustd) {
  const int b = blockIdx.y, s0 = blockIdx.x * 64;
  const int sl = threadIdx.x & 63, cg = threadIdx.x >> 6;
  const float* xp = x + (size_t)b * CC * SS + s0 + sl;
  float ps = 0.f, pq = 0.f;
  #pragma unroll 8
  for (int i = 0; i < 128; ++i) {
    const float v = xp[(size_t)(cg * 128 + i) * SS];
    ps += v; pq += v * v;
  }
  __shared__ float sred[2][4][64];
  sred[0][cg][sl] = ps; sred[1][cg][sl] = pq;
  __syncthreads();
  if (cg == 0) {
    const float s = (sred[0][0][sl] + sred[0][1][sl]) + (sred[0][2][sl] + sred[0][3][sl]);
    const float q = (sred[1][0][sl] + sred[1][1][sl]) + (sred[1][2][sl] + sred[1][3][sl]);
    const float mu = s * (1.0f / CC);
    const float rs = rsqrtf(q * (1.0f / CC) - mu * mu + 1e-5f);
    mustd[b * SS + s0 + sl] = make_float2(mu, rs);
  }
}

// ---------- LN1 apply + transpose: -> ln1 h/l + xs h/l (B,S,C) ---------------
__global__ __launch_bounds__(256) void ln1_apply(
    const float* __restrict__ x, const float2* __restrict__ mustd,
    const float* __restrict__ g, const float* __restrict__ be,
    unsigned short* __restrict__ yh, unsigned short* __restrict__ yl,
    unsigned short* __restrict__ xh, unsigned short* __restrict__ xl) {
  __shared__ float tile[32][33];
  const int b = blockIdx.z, c0 = blockIdx.y * 32, s0 = blockIdx.x * 32;
  const int tx = threadIdx.x, ty = threadIdx.y;
  const float* xb = x + ((size_t)b * CC + c0) * SS + s0;
  #pragma unroll
  for (int i = ty; i < 32; i += 8)
    tile[i][tx] = xb[(size_t)i * SS + tx];
  __syncthreads();
  const float gc = g[c0 + tx], bc = be[c0 + tx];
  #pragma unroll
  for (int i = ty; i < 32; i += 8) {
    const float2 ms = mustd[b * SS + s0 + i];
    const float v = tile[tx][i];
    const float y = (v - ms.x) * ms.y * gc + bc;
    const size_t oi = ((size_t)b * SS + s0 + i) * CC + c0 + tx;
    const unsigned short hy = f2bf(y);
    yh[oi] = hy; yl[oi] = f2bf(y - b2f(hy));
    const unsigned short hx = f2bf(v);
    xh[oi] = hx; xl[oi] = f2bf(v - b2f(hx));
  }
}

// ---------- LayerNorm (C=512) contiguous rows -> bf16 hi ---------------------
__global__ __launch_bounds__(256) void ln_bf16_k(const float* __restrict__ in,
                                                 const float* __restrict__ g,
                                                 const float* __restrict__ be,
                                                 unsigned short* __restrict__ outh) {
  size_t row = blockIdx.x;
  const float* r = in + row * CC;
  int t = threadIdx.x;
  float v0 = r[t], v1 = r[t + 256];
  float s = block_reduce_sum(v0 + v1);
  float mu = s * (1.0f / CC);
  float d0 = v0 - mu, d1 = v1 - mu;
  float vs = block_reduce_sum(d0 * d0 + d1 * d1);
  float rstd = rsqrtf(vs * (1.0f / CC) + 1e-5f);
  outh[row * CC + t]       = f2bf(d0 * rstd * g[t] + be[t]);
  outh[row * CC + t + 256] = f2bf(d1 * rstd * g[t + 256] + be[t + 256]);
}

// ---------- weight convert: fp32 -> bf16 hi/lo B^T (N,K) ---------------------
// Q_W / Q_b are pre-scaled by 1/sqrt(512)*log2(e): scores exit QK^T pre-scaled.
__global__ __launch_bounds__(256) void convert_weights(
    const float* __restrict__ QW, const float* __restrict__ KW,
    const float* __restrict__ VW, const float* __restrict__ OW,
    const float* __restrict__ W1, const float* __restrict__ W2,
    const float* __restrict__ Qb, const float* __restrict__ Kb,
    const float* __restrict__ Vb,
    unsigned short* __restrict__ BtQKh, unsigned short* __restrict__ BtQKl,
    unsigned short* __restrict__ BtVh,
    unsigned short* __restrict__ BtOh, unsigned short* __restrict__ BtOl,
    unsigned short* __restrict__ BtW1h, unsigned short* __restrict__ BtW2h,
    float* __restrict__ qkvb) {
  const float SCL = 0.044194173824159216f * 1.4426950408889634f;
  __shared__ float tile[32][33];
  const int p = blockIdx.z, wsel = p >> 3, sub = p & 7;
  const int k0 = blockIdx.x * 32, d0 = blockIdx.y * 32;
  const int tx = threadIdx.x, ty = threadIdx.y;
  const float* w; int rs; unsigned short *dh, *dl; int nbase; float mul = 1.0f;
  switch (wsel) {
    case 0:  w = QW + sub * 32768; rs = 64;  dh = BtQKh; dl = BtQKl;  nbase = sub * 64; mul = SCL; break;
    case 1:  w = KW + sub * 32768; rs = 64;  dh = BtQKh; dl = BtQKl;  nbase = 512 + sub * 64;  break;
    case 2:  w = VW + sub * 32768; rs = 64;  dh = BtVh;  dl = nullptr; nbase = sub * 64;       break;
    case 3:  w = OW + sub * 64;    rs = 512; dh = BtOh;  dl = BtOl;   nbase = sub * 64;        break;
    case 4:  w = W1 + sub * 64;    rs = 512; dh = BtW1h; dl = nullptr; nbase = sub * 64;       break;
    default: w = W2 + sub * 64;    rs = 512; dh = BtW2h; dl = nullptr; nbase = sub * 64;       break;
  }
  for (int i = ty; i < 32; i += 8)
    tile[i][tx] = w[(size_t)(k0 + i) * rs + d0 + tx];
  __syncthreads();
  for (int i = ty; i < 32; i += 8) {
    float f = tile[tx][i] * mul;
    unsigned short h = f2bf(f);
    size_t idx = (size_t)(nbase + d0 + i) * KD + k0 + tx;
    dh[idx] = h;
    if (dl) dl[idx] = f2bf(f - b2f(h));
  }
  if (p == 0 && blockIdx.x == 0 && blockIdx.y == 0) {
    int t = ty * 32 + tx;
    for (int i = t; i < 1536; i += 256)
      qkvb[i] = i < 512 ? Qb[i] * SCL : (i < 1024 ? Kb[i - 512] : Vb[i - 1024]);
  }
}

// ---------- fused QKV projection GEMM, 128x128 tiles, XCD-swizzled grid ------
// flat grid 768: xcd = f&7; g = f>>3; n-tile = g>>3 (B panel per XCD run),
// m-tile = ((g&7)<<3)|xcd  -> same-n blocks temporally adjacent per XCD.
__global__ __launch_bounds__(256) void gemm_qkv(
    const unsigned short* __restrict__ Ah, const unsigned short* __restrict__ Al,
    const unsigned short* __restrict__ Bth, const unsigned short* __restrict__ Btl,
    const float* __restrict__ bias,
    unsigned short* __restrict__ qkh, unsigned short* __restrict__ qkl,
    unsigned short* __restrict__ vt) {
  __shared__ __align__(16) unsigned short smem[4 * 128 * 32];
  unsigned short* As = smem;
  unsigned short* Bs = smem + 2 * 128 * 32;
  const int tid = threadIdx.x;
  const int w = tid >> 6, l = tid & 63, quad = l >> 4, lm = l & 15;
  const int f = blockIdx.x, xcd = f & 7, gidx = f >> 3;
  const int n0 = (gidx >> 3) * 128;
  const int m0 = (((gidx & 7) << 3) | xcd) * 128;
  const bool splitB = n0 < 1024;
  const int wm = (w >> 1) * 64, wn = (w & 1) * 64;
  const int srow = tid >> 2;
  const int sch = (((tid & 3) ^ (srow & 3)) * 8);
  const unsigned short* Agh = Ah + (size_t)(m0 + srow) * KD + sch;
  const unsigned short* Agl = Al + (size_t)(m0 + srow) * KD + sch;
  const unsigned short* Bgh = Bth + (size_t)(n0 + srow) * KD + sch;
  const unsigned short* Bgl = Btl + (size_t)(n0 + srow) * KD + sch;
  unsigned short* Aswh = As + w * 512;
  unsigned short* Aswl = As + 4096 + w * 512;
  unsigned short* Bswh = Bs + w * 512;
  unsigned short* Bswl = Bs + 4096 + w * 512;
  const int rch = ((quad ^ (lm & 3)) * 8);
  const f32x4 fzero = {0.f, 0.f, 0.f, 0.f};
  f32x4 acc[4][4];
  #pragma unroll
  for (int i = 0; i < 4; ++i)
    #pragma unroll
    for (int j = 0; j < 4; ++j) acc[i][j] = fzero;
  for (int k0 = 0; k0 < KD; k0 += 32) {
    __syncthreads();
    GLD_LDS(Agh + k0, Aswh);
    GLD_LDS(Agh + k0 + 64 * KD, Aswh + 2048);
    GLD_LDS(Agl + k0, Aswl);
    GLD_LDS(Agl + k0 + 64 * KD, Aswl + 2048);
    GLD_LDS(Bgh + k0, Bswh);
    GLD_LDS(Bgh + k0 + 64 * KD, Bswh + 2048);
    if (splitB) {
      GLD_LDS(Bgl + k0, Bswl);
      GLD_LDS(Bgl + k0 + 64 * KD, Bswl + 2048);
    }
    __syncthreads();
    short8 afh[4], afl[4], bfh[4], bfl[4];
    #pragma unroll
    for (int i = 0; i < 4; ++i) {
      afh[i] = *(const short8*)(As + (wm + i * 16 + lm) * 32 + rch);
      afl[i] = *(const short8*)(As + 4096 + (wm + i * 16 + lm) * 32 + rch);
    }
    #pragma unroll
    for (int j = 0; j < 4; ++j)
      bfh[j] = *(const short8*)(Bs + (wn + j * 16 + lm) * 32 + rch);
    if (splitB) {
      #pragma unroll
      for (int j = 0; j < 4; ++j)
        bfl[j] = *(const short8*)(Bs + 4096 + (wn + j * 16 + lm) * 32 + rch);
      #pragma unroll
      for (int i = 0; i < 4; ++i)
        #pragma unroll
        for (int j = 0; j < 4; ++j) {
          f32x4 t = acc[i][j];
          t = __builtin_amdgcn_mfma_f32_16x16x32_bf16(afh[i], bfh[j], t, 0, 0, 0);
          t = __builtin_amdgcn_mfma_f32_16x16x32_bf16(afh[i], bfl[j], t, 0, 0, 0);
          t = __builtin_amdgcn_mfma_f32_16x16x32_bf16(afl[i], bfh[j], t, 0, 0, 0);
          acc[i][j] = t;
        }
    } else {
      #pragma unroll
      for (int i = 0; i < 4; ++i)
        #pragma unroll
        for (int j = 0; j < 4; ++j)
          acc[i][j] = __builtin_amdgcn_mfma_f32_16x16x32_bf16(afh[i], bfh[j], acc[i][j], 0, 0, 0);
    }
  }
  if (splitB) {
    #pragma unroll
    for (int i = 0; i < 4; ++i) {
      const int row = m0 + wm + i * 16 + quad * 4;
      #pragma unroll
      for (int j = 0; j < 4; ++j) {
        const int ncol = n0 + wn + j * 16 + lm;
        const float bv = bias[ncol];
        #pragma unroll
        for (int r = 0; r < 4; ++r) {
          const float xv = acc[i][j][r] + bv;
          const size_t oi = (size_t)(row + r) * 1024 + ncol;
          unsigned short h = f2bf(xv);
          qkh[oi] = h;
          qkl[oi] = f2bf(xv - b2f(h));
        }
      }
    }
  } else {
    __syncthreads();
    #pragma unroll
    for (int i = 0; i < 4; ++i) {
      const int mlb = wm + i * 16 + quad * 4;
      #pragma unroll
      for (int j = 0; j < 4; ++j) {
        const int nl = wn + j * 16 + lm;
        const float bv = bias[n0 + nl];
        ushort4v pk;
        #pragma unroll
        for (int r = 0; r < 4; ++r) pk[r] = f2bf(acc[i][j][r] + bv);
        const int chunk = ((mlb >> 3) ^ (nl & 15));
        *(ushort4v*)(smem + nl * 128 + chunk * 8 + (mlb & 7)) = pk;
      }
    }
    __syncthreads();
    const int tn = tid >> 4, tc = tid & 15;
    const int bb2 = m0 >> 10, sbase = m0 & 1023;
    #pragma unroll
    for (int pass = 0; pass < 8; ++pass) {
      const int nl = pass * 16 + tn;
      const int hh = (n0 - 1024 + nl) >> 6, dd = nl & 63;
      short8 v8 = *(const short8*)(smem + nl * 128 + ((tc ^ (nl & 15)) * 8));
      *(short8*)(vt + ((size_t)(bb2 * 8 + hh) * 64 + dd) * 1024 + sbase + tc * 8) = v8;
    }
  }
}

// ---------- 64x64-tile GEMM, BK=64, GLD staging, XCD-swizzled grid -----------
// flat grid 1024: xcd=f&7; g=f>>3; n-tile=g>>4 (0..7), m-tile=((g&15)<<3)|xcd.
template<int SB, int GELU, int OUTMODE, int RESID, int TRANS>
__global__ __launch_bounds__(256) void gemm64(
    const unsigned short* __restrict__ Ah,
    const unsigned short* __restrict__ Bh, const unsigned short* __restrict__ Bl,
    const float* __restrict__ bias, const float* __restrict__ residf,
    const unsigned short* __restrict__ residh, const unsigned short* __restrict__ residl,
    unsigned short* __restrict__ outh, float* __restrict__ outf, int ldc) {
  constexpr int STAGE = (SB ? 3 : 2) * 8192;
  constexpr int TSIZE = TRANS ? 64 * 65 * 4 : 0;
  __shared__ __align__(16) unsigned char smem[STAGE > TSIZE ? STAGE : TSIZE];
  unsigned short* As  = (unsigned short*)smem;            // [64][64]
  unsigned short* Bs  = (unsigned short*)(smem + 8192);
  unsigned short* Bls = (unsigned short*)(smem + 16384);
  float (*ttile)[65]  = (float(*)[65])smem;
  const int tid = threadIdx.x;
  const int w = tid >> 6, l = tid & 63, quad = l >> 4, lm = l & 15;
  const int f = blockIdx.x, xcd = f & 7, gidx = f >> 3;
  const int n0 = (gidx >> 4) * 64;
  const int m0 = (((gidx & 15) << 3) | xcd) * 64;
  const int wm = (w >> 1) * 32, wn = (w & 1) * 32;
  const int srow8 = tid >> 3;
  const int sch8  = ((tid & 7) ^ (srow8 & 7)) * 8;
  const unsigned short* Ag  = Ah + (size_t)(m0 + srow8) * KD + sch8;
  const unsigned short* Bg  = Bh + (size_t)(n0 + srow8) * KD + sch8;
  const unsigned short* Bgl = SB ? Bl + (size_t)(n0 + srow8) * KD + sch8 : nullptr;
  const f32x4 fzero = {0.f, 0.f, 0.f, 0.f};
  f32x4 acc[2][2];
  #pragma unroll
  for (int i = 0; i < 2; ++i)
    #pragma unroll
    for (int j = 0; j < 2; ++j) acc[i][j] = fzero;
  for (int k0 = 0; k0 < KD; k0 += 64) {
    __syncthreads();
    GLD_LDS(Ag + k0, As + w * 512);
    GLD_LDS(Ag + k0 + 32 * KD, As + 2048 + w * 512);
    GLD_LDS(Bg + k0, Bs + w * 512);
    GLD_LDS(Bg + k0 + 32 * KD, Bs + 2048 + w * 512);
    if constexpr (SB) {
      GLD_LDS(Bgl + k0, Bls + w * 512);
      GLD_LDS(Bgl + k0 + 32 * KD, Bls + 2048 + w * 512);
    }
    __syncthreads();
    #pragma unroll
    for (int ks = 0; ks < 2; ++ks) {
      const int kc = ((ks * 4 + quad) ^ (lm & 7)) * 8;
      short8 af[2], bfh[2], bfl[2];
      #pragma unroll
      for (int i = 0; i < 2; ++i)
        af[i] = *(const short8*)(As + (wm + i * 16 + lm) * 64 + kc);
      #pragma unroll
      for (int j = 0; j < 2; ++j)
        bfh[j] = *(const short8*)(Bs + (wn + j * 16 + lm) * 64 + kc);
      if constexpr (SB) {
        #pragma unroll
        for (int j = 0; j < 2; ++j)
          bfl[j] = *(const short8*)(Bls + (wn + j * 16 + lm) * 64 + kc);
      }
      #pragma unroll
      for (int i = 0; i < 2; ++i)
        #pragma unroll
        for (int j = 0; j < 2; ++j) {
          f32x4 t = acc[i][j];
          t = __builtin_amdgcn_mfma_f32_16x16x32_bf16(af[i], bfh[j], t, 0, 0, 0);
          if constexpr (SB)
            t = __builtin_amdgcn_mfma_f32_16x16x32_bf16(af[i], bfl[j], t, 0, 0, 0);
          acc[i][j] = t;
        }
    }
  }
  if constexpr (TRANS) __syncthreads();
  #pragma unroll
  for (int i = 0; i < 2; ++i) {
    const int row = m0 + wm + i * 16 + quad * 4;
    #pragma unroll
    for (int j = 0; j < 2; ++j) {
      const int col = n0 + wn + j * 16 + lm;
      const float bv = bias[col];
      #pragma unroll
      for (int r = 0; r < 4; ++r) {
        float x = acc[i][j][r] + bv;
        if (GELU) x = 0.5f * x * (1.0f + erff(x * 0.70710678118654752f));
        const size_t ri = (size_t)(row + r) * CC + col;
        if (RESID == 1) x += residf[ri];
        if (RESID == 2) x += b2f(residh[ri]) + b2f(residl[ri]);
        if constexpr (TRANS) {
          ttile[wm + i * 16 + quad * 4 + r][wn + j * 16 + lm] = x;
        } else {
          const size_t oi = (size_t)(row + r) * ldc + col;
          if (OUTMODE == 0) outf[oi] = x;
          else outh[oi] = f2bf(x);
        }
      }
    }
  }
  if constexpr (TRANS) {
    __syncthreads();
    const int bi = m0 >> 10, s0 = m0 & 1023;
    const int s = tid & 63;
    #pragma unroll
    for (int c0 = 0; c0 < 64; c0 += 4) {
      const int col = c0 + (tid >> 6);
      outf[(size_t)(bi * 512 + n0 + col) * 1024 + s0 + s] = ttile[s][col];
    }
  }
}

// ---------- flash attention: XCD-swizzled (b,h) grouping ---------------------
// flat grid 1024: xcd=f&7; g=f>>3; bh = (xcd<<3)|(g>>4); q-tile = g&15.
// All 16 q-tiles of a (b,h) land on one XCD -> K/V fetched once per XCD L2.
__global__ __launch_bounds__(256) void attn_mfma(
    const unsigned short* __restrict__ QKh, const unsigned short* __restrict__ QKl,
    const unsigned short* __restrict__ Vt, unsigned short* __restrict__ Oh) {
  __shared__ __align__(16) unsigned short Ksh[64 * 64], Ksl[64 * 64];
  __shared__ __align__(16) unsigned short Vts[64 * 64];
  __shared__ __align__(16) unsigned short Ps[4 * 16 * 88];
  const int f = blockIdx.x, xcd = f & 7, gidx = f >> 3;
  const int bh = (xcd << 3) | (gidx >> 4);
  const int q0 = (gidx & 15) * 64, h = bh & 7, b = bh >> 3;
  const int tid = threadIdx.x, w = tid >> 6, l = tid & 63, quad = l >> 4, lm = l & 15;
  const int LDQ = 2 * CC;
  const size_t qkbase = (size_t)b * SS * LDQ;
  const int srow8 = tid >> 3;
  const int sch8  = ((tid & 7) ^ (srow8 & 7)) * 8;
  const unsigned short* Vg = Vt + ((size_t)(b * 8 + h) * 64 + srow8) * 1024 + sch8;
  short8 qh[2], ql[2];
  {
    const size_t qo = qkbase + (size_t)(q0 + w * 16 + lm) * LDQ + h * 64 + quad * 8;
    qh[0] = *(const short8*)(QKh + qo);
    qh[1] = *(const short8*)(QKh + qo + 32);
    ql[0] = *(const short8*)(QKl + qo);
    ql[1] = *(const short8*)(QKl + qo + 32);
  }
  short8 bones;
  #pragma unroll
  for (int u = 0; u < 8; ++u) bones[u] = (lm == 0) ? (short)0x3F80 : (short)0;
  const f32x4 fzero = {0.f, 0.f, 0.f, 0.f};
  float mrow[4];
  f32x4 oacc[5];
  #pragma unroll
  for (int r = 0; r < 4; ++r) mrow[r] = -1e30f;
  #pragma unroll
  for (int j = 0; j < 5; ++j) oacc[j] = fzero;
  unsigned short* Pw = Ps + w * (16 * 88);
  for (int kt = 0; kt < SS; kt += 64) {
    __syncthreads();
    {
      const unsigned short* kg  = QKh + qkbase + (size_t)(kt + srow8) * LDQ + CC + h * 64 + sch8;
      const unsigned short* kgl = QKl + qkbase + (size_t)(kt + srow8) * LDQ + CC + h * 64 + sch8;
      GLD_LDS(kg, Ksh + w * 512);
      GLD_LDS(kg + 32 * LDQ, Ksh + 2048 + w * 512);
      GLD_LDS(kgl, Ksl + w * 512);
      GLD_LDS(kgl + 32 * LDQ, Ksl + 2048 + w * 512);
      GLD_LDS(Vg + kt, Vts + w * 512);
      GLD_LDS(Vg + kt + 32 * 1024, Vts + 2048 + w * 512);
    }
    __syncthreads();
    f32x4 sc[4];
    #pragma unroll
    for (int j = 0; j < 4; ++j) sc[j] = fzero;
    #pragma unroll
    for (int st = 0; st < 2; ++st) {
      const int kc = ((st * 4 + quad) ^ (lm & 7)) * 8;
      #pragma unroll
      for (int j = 0; j < 4; ++j) {
        short8 kh = *(const short8*)(Ksh + (j * 16 + lm) * 64 + kc);
        short8 kl = *(const short8*)(Ksl + (j * 16 + lm) * 64 + kc);
        f32x4 t = sc[j];
        t = __builtin_amdgcn_mfma_f32_16x16x32_bf16(qh[st], kh, t, 0, 0, 0);
        t = __builtin_amdgcn_mfma_f32_16x16x32_bf16(qh[st], kl, t, 0, 0, 0);
        t = __builtin_amdgcn_mfma_f32_16x16x32_bf16(ql[st], kh, t, 0, 0, 0);
        sc[j] = t;
      }
    }
    #pragma unroll
    for (int r = 0; r < 4; ++r) {
      float mt = fmaxf(fmaxf(sc[0][r], sc[1][r]), fmaxf(sc[2][r], sc[3][r]));
      #pragma unroll
      for (int mask = 1; mask < 16; mask <<= 1) mt = fmaxf(mt, __shfl_xor(mt, mask, 64));
      const float mn = fmaxf(mrow[r], mt);
      const float alpha = exp2f(mrow[r] - mn);
      mrow[r] = mn;
      #pragma unroll
      for (int j = 0; j < 4; ++j) sc[j][r] = exp2f(sc[j][r] - mn);
      #pragma unroll
      for (int j = 0; j < 5; ++j) oacc[j][r] *= alpha;
    }
    #pragma unroll
    for (int r = 0; r < 4; ++r)
      #pragma unroll
      for (int j = 0; j < 4; ++j) {
        union { float f; unsigned int u; } pc; pc.f = sc[j][r];
        Pw[(quad * 4 + r) * 88 + j * 16 + lm] = (unsigned short)(pc.u >> 16);
      }
    #pragma unroll
    for (int st = 0; st < 2; ++st) {
      short8 ap = *(const short8*)(Pw + lm * 88 + st * 32 + quad * 8);
      const int kc = ((st * 4 + quad) ^ (lm & 7)) * 8;
      #pragma unroll
      for (int j = 0; j < 4; ++j) {
        short8 vv = *(const short8*)(Vts + (j * 16 + lm) * 64 + kc);
        oacc[j] = __builtin_amdgcn_mfma_f32_16x16x32_bf16(ap, vv, oacc[j], 0, 0, 0);
      }
      oacc[4] = __builtin_amdgcn_mfma_f32_16x16x32_bf16(ap, bones, oacc[4], 0, 0, 0);
    }
  }
  float inv[4];
  #pragma unroll
  for (int r = 0; r < 4; ++r) {
    const float lv = __shfl(oacc[4][r], l & 48, 64);
    inv[r] = 1.f / lv;
  }
  const size_t obase =
      (size_t)b * SS * CC + (size_t)(q0 + w * 16 + quad * 4) * CC + h * 64 + lm;
  #pragma unroll
  for (int j = 0; j < 4; ++j)
    #pragma unroll
    for (int r = 0; r < 4; ++r)
      Oh[obase + (size_t)r * CC + j * 16] = f2bf(oacc[j][r] * inv[r]);
}

extern "C" void kernel_launch(void* const* d_in, const int* in_sizes, int n_in,
                              void* d_out, int out_size, void* d_ws, size_t ws_size,
                              hipStream_t stream) {
  const float* x    = (const float*)d_in[0];
  const float* K_W  = (const float*)d_in[2];
  const float* K_b  = (const float*)d_in[3];
  const float* Q_W  = (const float*)d_in[4];
  const float* Q_b  = (const float*)d_in[5];
  const float* V_W  = (const float*)d_in[6];
  const float* V_b  = (const float*)d_in[7];
  const float* O_W  = (const float*)d_in[8];
  const float* O_b  = (const float*)d_in[9];
  const float* ln1g = (const float*)d_in[10];
  const float* ln1b = (const float*)d_in[11];
  const float* ln2g = (const float*)d_in[12];
  const float* ln2b = (const float*)d_in[13];
  const float* W1   = (const float*)d_in[14];
  const float* b1   = (const float*)d_in[15];
  const float* W2   = (const float*)d_in[16];
  const float* b2   = (const float*)d_in[17];
  float* out = (float*)d_out;

  unsigned char* ws = (unsigned char*)d_ws;
  const size_t MB = 1u << 20;
  unsigned short* qkh   = (unsigned short*)(ws);             // (B,S,1024) 16MB
  unsigned short* qkl   = (unsigned short*)(ws + 16 * MB);   // 16MB
  unsigned short* vt    = (unsigned short*)(ws + 32 * MB);   // (B,NH,HD,S) 8MB
  unsigned short* ln1h  = (unsigned short*)(ws + 40 * MB);   // 8MB
  unsigned short* ln1l  = (unsigned short*)(ws + 48 * MB);   // 8MB
  unsigned short* xsh   = (unsigned short*)(ws + 56 * MB);   // 8MB
  unsigned short* xsl   = (unsigned short*)(ws + 64 * MB);   // 8MB
  unsigned short* oh    = ln1h;
  float* out1           = (float*)(ws + 72 * MB);            // 16MB
  unsigned short* ln2h  = qkh;
  unsigned short* geluh = (unsigned short*)(ws + 8 * MB);
  unsigned short* BtAll = (unsigned short*)(ws + 88 * MB);
  unsigned short* BtQKh = BtAll;
  unsigned short* BtVh  = BtAll + 1024 * 512;
  unsigned short* BtQKl = BtVh + 512 * 512;
  unsigned short* BtOh  = BtQKl + 1024 * 512;
  unsigned short* BtOl  = BtOh + 512 * 512;
  unsigned short* BtW1h = BtOl + 512 * 512;
  unsigned short* BtW2h = BtW1h + 512 * 512;
  float* qkvb           = (float*)(BtW2h + 512 * 512);
  float2* mustd         = (float2*)(ws + 96 * MB);

  dim3 tb32(32, 8);
  convert_weights<<<dim3(16, 2, 48), tb32, 0, stream>>>(
      Q_W, K_W, V_W, O_W, W1, W2, Q_b, K_b, V_b,
      BtQKh, BtQKl, BtVh, BtOh, BtOl, BtW1h, BtW2h, qkvb);
  ln1_stats<<<dim3(SS / 64, BB), 256, 0, stream>>>(x, mustd);
  ln1_apply<<<dim3(SS / 32, CC / 32, BB), tb32, 0, stream>>>(
      x, mustd, ln1g, ln1b, ln1h, ln1l, xsh, xsl);
  gemm_qkv<<<768, 256, 0, stream>>>(
      ln1h, ln1l, BtAll, BtQKl, qkvb, qkh, qkl, vt);
  attn_mfma<<<1024, 256, 0, stream>>>(qkh, qkl, vt, oh);
  gemm64<1, 0, 0, 2, 0><<<1024, 256, 0, stream>>>(
      oh, BtOh, BtOl, O_b, nullptr, xsh, xsl, nullptr, out1, CC);
  ln_bf16_k<<<BB * SS, 256, 0, stream>>>(out1, ln2g, ln2b, ln2h);
  gemm64<0, 1, 1, 0, 0><<<1024, 256, 0, stream>>>(
      ln2h, BtW1h, nullptr, b1, nullptr, nullptr, nullptr, geluh, nullptr, CC);
  gemm64<0, 0, 0, 1, 1><<<1024, 256, 0, stream>>>(
      geluh, BtW2h, nullptr, b2, out1, nullptr, nullptr, nullptr, out, CC);
}

// Round 12
// 269.718 us; speedup vs baseline: 1.2589x; 1.0583x over previous
//
#include <hip/hip_runtime.h>
#include <math.h>

#define BB 8
#define CC 512
#define SS 1024
#define NHH 8
#define HDD 64
#define KD 512

typedef __attribute__((ext_vector_type(8))) short short8;
typedef __attribute__((ext_vector_type(4))) float f32x4;
typedef __attribute__((ext_vector_type(4))) unsigned short ushort4v;

__device__ __forceinline__ unsigned short f2bf(float x) {
  union { float f; unsigned int u; } c; c.f = x;
  unsigned int r = (c.u + 0x7FFFu + ((c.u >> 16) & 1u)) >> 16;
  return (unsigned short)r;
}
__device__ __forceinline__ float b2f(unsigned short h) {
  union { unsigned int u; float f; } c; c.u = ((unsigned int)h) << 16; return c.f;
}

#define GLD_LDS(gp, lp) __builtin_amdgcn_global_load_lds( \
    (const __attribute__((address_space(1))) void*)(gp),  \
    (__attribute__((address_space(3))) void*)(lp), 16, 0, 0)

// ---------- block-wide sum over 256 threads (4 waves) ----------
__device__ __forceinline__ float block_reduce_sum(float v) {
  __shared__ float sm[4];
  #pragma unroll
  for (int o = 32; o > 0; o >>= 1) v += __shfl_down(v, o, 64);
  if ((threadIdx.x & 63) == 0) sm[threadIdx.x >> 6] = v;
  __syncthreads();
  float r = (sm[0] + sm[1]) + (sm[2] + sm[3]);
  __syncthreads();
  return r;
}

// ---------- LN1 apply + transpose: -> ln1 h/l + xs h/l (B,S,C) ---------------
__global__ __launch_bounds__(256) void ln1_apply(
    const float* __restrict__ x, const float2* __restrict__ mustd,
    const float* __restrict__ g, const float* __restrict__ be,
    unsigned short* __restrict__ yh, unsigned short* __restrict__ yl,
    unsigned short* __restrict__ xh, unsigned short* __restrict__ xl) {
  __shared__ float tile[32][33];
  const int b = blockIdx.z, c0 = blockIdx.y * 32, s0 = blockIdx.x * 32;
  const int tx = threadIdx.x, ty = threadIdx.y;
  const float* xb = x + ((size_t)b * CC + c0) * SS + s0;
  #pragma unroll
  for (int i = ty; i < 32; i += 8)
    tile[i][tx] = xb[(size_t)i * SS + tx];
  __syncthreads();
  const float gc = g[c0 + tx], bc = be[c0 + tx];
  #pragma unroll
  for (int i = ty; i < 32; i += 8) {
    const float2 ms = mustd[b * SS + s0 + i];
    const float v = tile[tx][i];
    const float y = (v - ms.x) * ms.y * gc + bc;
    const size_t oi = ((size_t)b * SS + s0 + i) * CC + c0 + tx;
    const unsigned short hy = f2bf(y);
    yh[oi] = hy; yl[oi] = f2bf(y - b2f(hy));
    const unsigned short hx = f2bf(v);
    xh[oi] = hx; xl[oi] = f2bf(v - b2f(hx));
  }
}

// ---------- LayerNorm (C=512) contiguous rows -> bf16 hi ---------------------
__global__ __launch_bounds__(256) void ln_bf16_k(const float* __restrict__ in,
                                                 const float* __restrict__ g,
                                                 const float* __restrict__ be,
                                                 unsigned short* __restrict__ outh) {
  size_t row = blockIdx.x;
  const float* r = in + row * CC;
  int t = threadIdx.x;
  float v0 = r[t], v1 = r[t + 256];
  float s = block_reduce_sum(v0 + v1);
  float mu = s * (1.0f / CC);
  float d0 = v0 - mu, d1 = v1 - mu;
  float vs = block_reduce_sum(d0 * d0 + d1 * d1);
  float rstd = rsqrtf(vs * (1.0f / CC) + 1e-5f);
  outh[row * CC + t]       = f2bf(d0 * rstd * g[t] + be[t]);
  outh[row * CC + t + 256] = f2bf(d1 * rstd * g[t + 256] + be[t + 256]);
}

// ---------- weight convert + LN1 stats, one flat launch ----------------------
// blocks [0,1536): weight panels (as before); blocks [1536,1664): ln1 stats.
// Q_W / Q_b pre-scaled by 1/sqrt(512)*log2(e).
__global__ __launch_bounds__(256) void convert_and_stats(
    const float* __restrict__ QW, const float* __restrict__ KW,
    const float* __restrict__ VW, const float* __restrict__ OW,
    const float* __restrict__ W1, const float* __restrict__ W2,
    const float* __restrict__ Qb, const float* __restrict__ Kb,
    const float* __restrict__ Vb,
    unsigned short* __restrict__ BtQKh, unsigned short* __restrict__ BtQKl,
    unsigned short* __restrict__ BtVh,
    unsigned short* __restrict__ BtOh, unsigned short* __restrict__ BtOl,
    unsigned short* __restrict__ BtW1h, unsigned short* __restrict__ BtW2h,
    float* __restrict__ qkvb,
    const float* __restrict__ x, float2* __restrict__ mustd) {
  const int bid = blockIdx.x;
  if (bid < 1536) {
    const float SCL = 0.044194173824159216f * 1.4426950408889634f;
    __shared__ float tile[32][33];
    const int bx = bid & 15, by = (bid >> 4) & 1, p = bid >> 5;
    const int wsel = p >> 3, sub = p & 7;
    const int k0 = bx * 32, d0 = by * 32;
    const int tx = threadIdx.x & 31, ty = threadIdx.x >> 5;
    const float* w; int rs; unsigned short *dh, *dl; int nbase; float mul = 1.0f;
    switch (wsel) {
      case 0:  w = QW + sub * 32768; rs = 64;  dh = BtQKh; dl = BtQKl;  nbase = sub * 64; mul = SCL; break;
      case 1:  w = KW + sub * 32768; rs = 64;  dh = BtQKh; dl = BtQKl;  nbase = 512 + sub * 64;  break;
      case 2:  w = VW + sub * 32768; rs = 64;  dh = BtVh;  dl = nullptr; nbase = sub * 64;       break;
      case 3:  w = OW + sub * 64;    rs = 512; dh = BtOh;  dl = BtOl;   nbase = sub * 64;        break;
      case 4:  w = W1 + sub * 64;    rs = 512; dh = BtW1h; dl = nullptr; nbase = sub * 64;       break;
      default: w = W2 + sub * 64;    rs = 512; dh = BtW2h; dl = nullptr; nbase = sub * 64;       break;
    }
    for (int i = ty; i < 32; i += 8)
      tile[i][tx] = w[(size_t)(k0 + i) * rs + d0 + tx];
    __syncthreads();
    for (int i = ty; i < 32; i += 8) {
      float f = tile[tx][i] * mul;
      unsigned short h = f2bf(f);
      size_t idx = (size_t)(nbase + d0 + i) * KD + k0 + tx;
      dh[idx] = h;
      if (dl) dl[idx] = f2bf(f - b2f(h));
    }
    if (bid == 0) {
      int t = threadIdx.x;
      for (int i = t; i < 1536; i += 256)
        qkvb[i] = i < 512 ? Qb[i] * SCL : (i < 1024 ? Kb[i - 512] : Vb[i - 1024]);
    }
  } else {
    const int bid2 = bid - 1536;
    const int b = bid2 >> 4, s0 = (bid2 & 15) * 64;
    const int sl = threadIdx.x & 63, cg = threadIdx.x >> 6;
    const float* xp = x + (size_t)b * CC * SS + s0 + sl;
    float ps = 0.f, pq = 0.f;
    #pragma unroll 8
    for (int i = 0; i < 128; ++i) {
      const float v = xp[(size_t)(cg * 128 + i) * SS];
      ps += v; pq += v * v;
    }
    __shared__ float sred[2][4][64];
    sred[0][cg][sl] = ps; sred[1][cg][sl] = pq;
    __syncthreads();
    if (cg == 0) {
      const float s = (sred[0][0][sl] + sred[0][1][sl]) + (sred[0][2][sl] + sred[0][3][sl]);
      const float q = (sred[1][0][sl] + sred[1][1][sl]) + (sred[1][2][sl] + sred[1][3][sl]);
      const float mu = s * (1.0f / CC);
      const float rs = rsqrtf(q * (1.0f / CC) - mu * mu + 1e-5f);
      mustd[b * SS + s0 + sl] = make_float2(mu, rs);
    }
  }
}

// ---------- fused QKV projection GEMM, 128x128 tiles, XCD-swizzled grid ------
__global__ __launch_bounds__(256) void gemm_qkv(
    const unsigned short* __restrict__ Ah, const unsigned short* __restrict__ Al,
    const unsigned short* __restrict__ Bth, const unsigned short* __restrict__ Btl,
    const float* __restrict__ bias,
    unsigned short* __restrict__ qkh, unsigned short* __restrict__ qkl,
    unsigned short* __restrict__ vt) {
  __shared__ __align__(16) unsigned short smem[4 * 128 * 32];
  unsigned short* As = smem;
  unsigned short* Bs = smem + 2 * 128 * 32;
  const int tid = threadIdx.x;
  const int w = tid >> 6, l = tid & 63, quad = l >> 4, lm = l & 15;
  const int f = blockIdx.x, xcd = f & 7, gidx = f >> 3;
  const int n0 = (gidx >> 3) * 128;
  const int m0 = (((gidx & 7) << 3) | xcd) * 128;
  const bool splitB = n0 < 1024;
  const int wm = (w >> 1) * 64, wn = (w & 1) * 64;
  const int srow = tid >> 2;
  const int sch = (((tid & 3) ^ (srow & 3)) * 8);
  const unsigned short* Agh = Ah + (size_t)(m0 + srow) * KD + sch;
  const unsigned short* Agl = Al + (size_t)(m0 + srow) * KD + sch;
  const unsigned short* Bgh = Bth + (size_t)(n0 + srow) * KD + sch;
  const unsigned short* Bgl = Btl + (size_t)(n0 + srow) * KD + sch;
  unsigned short* Aswh = As + w * 512;
  unsigned short* Aswl = As + 4096 + w * 512;
  unsigned short* Bswh = Bs + w * 512;
  unsigned short* Bswl = Bs + 4096 + w * 512;
  const int rch = ((quad ^ (lm & 3)) * 8);
  const f32x4 fzero = {0.f, 0.f, 0.f, 0.f};
  f32x4 acc[4][4];
  #pragma unroll
  for (int i = 0; i < 4; ++i)
    #pragma unroll
    for (int j = 0; j < 4; ++j) acc[i][j] = fzero;
  for (int k0 = 0; k0 < KD; k0 += 32) {
    __syncthreads();
    GLD_LDS(Agh + k0, Aswh);
    GLD_LDS(Agh + k0 + 64 * KD, Aswh + 2048);
    GLD_LDS(Agl + k0, Aswl);
    GLD_LDS(Agl + k0 + 64 * KD, Aswl + 2048);
    GLD_LDS(Bgh + k0, Bswh);
    GLD_LDS(Bgh + k0 + 64 * KD, Bswh + 2048);
    if (splitB) {
      GLD_LDS(Bgl + k0, Bswl);
      GLD_LDS(Bgl + k0 + 64 * KD, Bswl + 2048);
    }
    __syncthreads();
    short8 afh[4], afl[4], bfh[4], bfl[4];
    #pragma unroll
    for (int i = 0; i < 4; ++i) {
      afh[i] = *(const short8*)(As + (wm + i * 16 + lm) * 32 + rch);
      afl[i] = *(const short8*)(As + 4096 + (wm + i * 16 + lm) * 32 + rch);
    }
    #pragma unroll
    for (int j = 0; j < 4; ++j)
      bfh[j] = *(const short8*)(Bs + (wn + j * 16 + lm) * 32 + rch);
    if (splitB) {
      #pragma unroll
      for (int j = 0; j < 4; ++j)
        bfl[j] = *(const short8*)(Bs + 4096 + (wn + j * 16 + lm) * 32 + rch);
      #pragma unroll
      for (int i = 0; i < 4; ++i)
        #pragma unroll
        for (int j = 0; j < 4; ++j) {
          f32x4 t = acc[i][j];
          t = __builtin_amdgcn_mfma_f32_16x16x32_bf16(afh[i], bfh[j], t, 0, 0, 0);
          t = __builtin_amdgcn_mfma_f32_16x16x32_bf16(afh[i], bfl[j], t, 0, 0, 0);
          t = __builtin_amdgcn_mfma_f32_16x16x32_bf16(afl[i], bfh[j], t, 0, 0, 0);
          acc[i][j] = t;
        }
    } else {
      #pragma unroll
      for (int i = 0; i < 4; ++i)
        #pragma unroll
        for (int j = 0; j < 4; ++j)
          acc[i][j] = __builtin_amdgcn_mfma_f32_16x16x32_bf16(afh[i], bfh[j], acc[i][j], 0, 0, 0);
    }
  }
  if (splitB) {
    #pragma unroll
    for (int i = 0; i < 4; ++i) {
      const int row = m0 + wm + i * 16 + quad * 4;
      #pragma unroll
      for (int j = 0; j < 4; ++j) {
        const int ncol = n0 + wn + j * 16 + lm;
        const float bv = bias[ncol];
        #pragma unroll
        for (int r = 0; r < 4; ++r) {
          const float xv = acc[i][j][r] + bv;
          const size_t oi = (size_t)(row + r) * 1024 + ncol;
          unsigned short h = f2bf(xv);
          qkh[oi] = h;
          qkl[oi] = f2bf(xv - b2f(h));
        }
      }
    }
  } else {
    __syncthreads();
    #pragma unroll
    for (int i = 0; i < 4; ++i) {
      const int mlb = wm + i * 16 + quad * 4;
      #pragma unroll
      for (int j = 0; j < 4; ++j) {
        const int nl = wn + j * 16 + lm;
        const float bv = bias[n0 + nl];
        ushort4v pk;
        #pragma unroll
        for (int r = 0; r < 4; ++r) pk[r] = f2bf(acc[i][j][r] + bv);
        const int chunk = ((mlb >> 3) ^ (nl & 15));
        *(ushort4v*)(smem + nl * 128 + chunk * 8 + (mlb & 7)) = pk;
      }
    }
    __syncthreads();
    const int tn = tid >> 4, tc = tid & 15;
    const int bb2 = m0 >> 10, sbase = m0 & 1023;
    #pragma unroll
    for (int pass = 0; pass < 8; ++pass) {
      const int nl = pass * 16 + tn;
      const int hh = (n0 - 1024 + nl) >> 6, dd = nl & 63;
      short8 v8 = *(const short8*)(smem + nl * 128 + ((tc ^ (nl & 15)) * 8));
      *(short8*)(vt + ((size_t)(bb2 * 8 + hh) * 64 + dd) * 1024 + sbase + tc * 8) = v8;
    }
  }
}

// ---------- 64x64-tile GEMM, BK=64, GLD staging, XCD-swizzled grid -----------
template<int SB, int GELU, int OUTMODE, int RESID, int TRANS>
__global__ __launch_bounds__(256) void gemm64(
    const unsigned short* __restrict__ Ah,
    const unsigned short* __restrict__ Bh, const unsigned short* __restrict__ Bl,
    const float* __restrict__ bias, const float* __restrict__ residf,
    const unsigned short* __restrict__ residh, const unsigned short* __restrict__ residl,
    unsigned short* __restrict__ outh, float* __restrict__ outf, int ldc) {
  constexpr int STAGE = (SB ? 3 : 2) * 8192;
  constexpr int TSIZE = TRANS ? 64 * 65 * 4 : 0;
  __shared__ __align__(16) unsigned char smem[STAGE > TSIZE ? STAGE : TSIZE];
  unsigned short* As  = (unsigned short*)smem;
  unsigned short* Bs  = (unsigned short*)(smem + 8192);
  unsigned short* Bls = (unsigned short*)(smem + 16384);
  float (*ttile)[65]  = (float(*)[65])smem;
  const int tid = threadIdx.x;
  const int w = tid >> 6, l = tid & 63, quad = l >> 4, lm = l & 15;
  const int f = blockIdx.x, xcd = f & 7, gidx = f >> 3;
  const int n0 = (gidx >> 4) * 64;
  const int m0 = (((gidx & 15) << 3) | xcd) * 64;
  const int wm = (w >> 1) * 32, wn = (w & 1) * 32;
  const int srow8 = tid >> 3;
  const int sch8  = ((tid & 7) ^ (srow8 & 7)) * 8;
  const unsigned short* Ag  = Ah + (size_t)(m0 + srow8) * KD + sch8;
  const unsigned short* Bg  = Bh + (size_t)(n0 + srow8) * KD + sch8;
  const unsigned short* Bgl = SB ? Bl + (size_t)(n0 + srow8) * KD + sch8 : nullptr;
  const f32x4 fzero = {0.f, 0.f, 0.f, 0.f};
  f32x4 acc[2][2];
  #pragma unroll
  for (int i = 0; i < 2; ++i)
    #pragma unroll
    for (int j = 0; j < 2; ++j) acc[i][j] = fzero;
  for (int k0 = 0; k0 < KD; k0 += 64) {
    __syncthreads();
    GLD_LDS(Ag + k0, As + w * 512);
    GLD_LDS(Ag + k0 + 32 * KD, As + 2048 + w * 512);
    GLD_LDS(Bg + k0, Bs + w * 512);
    GLD_LDS(Bg + k0 + 32 * KD, Bs + 2048 + w * 512);
    if constexpr (SB) {
      GLD_LDS(Bgl + k0, Bls + w * 512);
      GLD_LDS(Bgl + k0 + 32 * KD, Bls + 2048 + w * 512);
    }
    __syncthreads();
    #pragma unroll
    for (int ks = 0; ks < 2; ++ks) {
      const int kc = ((ks * 4 + quad) ^ (lm & 7)) * 8;
      short8 af[2], bfh[2], bfl[2];
      #pragma unroll
      for (int i = 0; i < 2; ++i)
        af[i] = *(const short8*)(As + (wm + i * 16 + lm) * 64 + kc);
      #pragma unroll
      for (int j = 0; j < 2; ++j)
        bfh[j] = *(const short8*)(Bs + (wn + j * 16 + lm) * 64 + kc);
      if constexpr (SB) {
        #pragma unroll
        for (int j = 0; j < 2; ++j)
          bfl[j] = *(const short8*)(Bls + (wn + j * 16 + lm) * 64 + kc);
      }
      #pragma unroll
      for (int i = 0; i < 2; ++i)
        #pragma unroll
        for (int j = 0; j < 2; ++j) {
          f32x4 t = acc[i][j];
          t = __builtin_amdgcn_mfma_f32_16x16x32_bf16(af[i], bfh[j], t, 0, 0, 0);
          if constexpr (SB)
            t = __builtin_amdgcn_mfma_f32_16x16x32_bf16(af[i], bfl[j], t, 0, 0, 0);
          acc[i][j] = t;
        }
    }
  }
  if constexpr (TRANS) __syncthreads();
  #pragma unroll
  for (int i = 0; i < 2; ++i) {
    const int row = m0 + wm + i * 16 + quad * 4;
    #pragma unroll
    for (int j = 0; j < 2; ++j) {
      const int col = n0 + wn + j * 16 + lm;
      const float bv = bias[col];
      #pragma unroll
      for (int r = 0; r < 4; ++r) {
        float x = acc[i][j][r] + bv;
        if (GELU) x = 0.5f * x * (1.0f + erff(x * 0.70710678118654752f));
        const size_t ri = (size_t)(row + r) * CC + col;
        if (RESID == 1) x += residf[ri];
        if (RESID == 2) x += b2f(residh[ri]) + b2f(residl[ri]);
        if constexpr (TRANS) {
          ttile[wm + i * 16 + quad * 4 + r][wn + j * 16 + lm] = x;
        } else {
          const size_t oi = (size_t)(row + r) * ldc + col;
          if (OUTMODE == 0) outf[oi] = x;
          else outh[oi] = f2bf(x);
        }
      }
    }
  }
  if constexpr (TRANS) {
    __syncthreads();
    const int bi = m0 >> 10, s0 = m0 & 1023;
    const int s = tid & 63;
    #pragma unroll
    for (int c0 = 0; c0 < 64; c0 += 4) {
      const int col = c0 + (tid >> 6);
      outf[(size_t)(bi * 512 + n0 + col) * 1024 + s0 + s] = ttile[s][col];
    }
  }
}

// ---------- flash attention: XCD-swizzled, conditional rescale ---------------
__global__ __launch_bounds__(256) void attn_mfma(
    const unsigned short* __restrict__ QKh, const unsigned short* __restrict__ QKl,
    const unsigned short* __restrict__ Vt, unsigned short* __restrict__ Oh) {
  __shared__ __align__(16) unsigned short Ksh[64 * 64], Ksl[64 * 64];
  __shared__ __align__(16) unsigned short Vts[64 * 64];
  __shared__ __align__(16) unsigned short Ps[4 * 16 * 88];
  const int f = blockIdx.x, xcd = f & 7, gidx = f >> 3;
  const int bh = (xcd << 3) | (gidx >> 4);
  const int q0 = (gidx & 15) * 64, h = bh & 7, b = bh >> 3;
  const int tid = threadIdx.x, w = tid >> 6, l = tid & 63, quad = l >> 4, lm = l & 15;
  const int LDQ = 2 * CC;
  const size_t qkbase = (size_t)b * SS * LDQ;
  const int srow8 = tid >> 3;
  const int sch8  = ((tid & 7) ^ (srow8 & 7)) * 8;
  const unsigned short* Vg = Vt + ((size_t)(b * 8 + h) * 64 + srow8) * 1024 + sch8;
  short8 qh[2], ql[2];
  {
    const size_t qo = qkbase + (size_t)(q0 + w * 16 + lm) * LDQ + h * 64 + quad * 8;
    qh[0] = *(const short8*)(QKh + qo);
    qh[1] = *(const short8*)(QKh + qo + 32);
    ql[0] = *(const short8*)(QKl + qo);
    ql[1] = *(const short8*)(QKl + qo + 32);
  }
  short8 bones;
  #pragma unroll
  for (int u = 0; u < 8; ++u) bones[u] = (lm == 0) ? (short)0x3F80 : (short)0;
  const f32x4 fzero = {0.f, 0.f, 0.f, 0.f};
  float mrow[4];
  f32x4 oacc[5];
  #pragma unroll
  for (int r = 0; r < 4; ++r) mrow[r] = -1e30f;
  #pragma unroll
  for (int j = 0; j < 5; ++j) oacc[j] = fzero;
  unsigned short* Pw = Ps + w * (16 * 88);
  for (int kt = 0; kt < SS; kt += 64) {
    __syncthreads();
    {
      const unsigned short* kg  = QKh + qkbase + (size_t)(kt + srow8) * LDQ + CC + h * 64 + sch8;
      const unsigned short* kgl = QKl + qkbase + (size_t)(kt + srow8) * LDQ + CC + h * 64 + sch8;
      GLD_LDS(kg, Ksh + w * 512);
      GLD_LDS(kg + 32 * LDQ, Ksh + 2048 + w * 512);
      GLD_LDS(kgl, Ksl + w * 512);
      GLD_LDS(kgl + 32 * LDQ, Ksl + 2048 + w * 512);
      GLD_LDS(Vg + kt, Vts + w * 512);
      GLD_LDS(Vg + kt + 32 * 1024, Vts + 2048 + w * 512);
    }
    __syncthreads();
    f32x4 sc[4];
    {  // st = 0 : first MFMA consumes the loop-invariant zero vector
      const int kc = (quad ^ (lm & 7)) * 8;
      #pragma unroll
      for (int j = 0; j < 4; ++j) {
        short8 kh = *(const short8*)(Ksh + (j * 16 + lm) * 64 + kc);
        short8 kl = *(const short8*)(Ksl + (j * 16 + lm) * 64 + kc);
        f32x4 t = __builtin_amdgcn_mfma_f32_16x16x32_bf16(qh[0], kh, fzero, 0, 0, 0);
        t = __builtin_amdgcn_mfma_f32_16x16x32_bf16(qh[0], kl, t, 0, 0, 0);
        t = __builtin_amdgcn_mfma_f32_16x16x32_bf16(ql[0], kh, t, 0, 0, 0);
        sc[j] = t;
      }
    }
    {  // st = 1
      const int kc = ((4 + quad) ^ (lm & 7)) * 8;
      #pragma unroll
      for (int j = 0; j < 4; ++j) {
        short8 kh = *(const short8*)(Ksh + (j * 16 + lm) * 64 + kc);
        short8 kl = *(const short8*)(Ksl + (j * 16 + lm) * 64 + kc);
        f32x4 t = sc[j];
        t = __builtin_amdgcn_mfma_f32_16x16x32_bf16(qh[1], kh, t, 0, 0, 0);
        t = __builtin_amdgcn_mfma_f32_16x16x32_bf16(qh[1], kl, t, 0, 0, 0);
        t = __builtin_amdgcn_mfma_f32_16x16x32_bf16(ql[1], kh, t, 0, 0, 0);
        sc[j] = t;
      }
    }
    // running max; rescale only if any row's max advanced (alpha==1 otherwise)
    float mnew[4];
    bool chg = false;
    #pragma unroll
    for (int r = 0; r < 4; ++r) {
      float mt = fmaxf(fmaxf(sc[0][r], sc[1][r]), fmaxf(sc[2][r], sc[3][r]));
      #pragma unroll
      for (int mask = 1; mask < 16; mask <<= 1) mt = fmaxf(mt, __shfl_xor(mt, mask, 64));
      mnew[r] = fmaxf(mrow[r], mt);
      chg = chg || (mnew[r] > mrow[r]);
    }
    if (__any(chg)) {
      #pragma unroll
      for (int r = 0; r < 4; ++r) {
        const float alpha = exp2f(mrow[r] - mnew[r]);
        mrow[r] = mnew[r];
        #pragma unroll
        for (int j = 0; j < 5; ++j) oacc[j][r] *= alpha;
      }
    }
    #pragma unroll
    for (int r = 0; r < 4; ++r)
      #pragma unroll
      for (int j = 0; j < 4; ++j) sc[j][r] = exp2f(sc[j][r] - mrow[r]);
    #pragma unroll
    for (int r = 0; r < 4; ++r)
      #pragma unroll
      for (int j = 0; j < 4; ++j) {
        union { float f; unsigned int u; } pc; pc.f = sc[j][r];
        Pw[(quad * 4 + r) * 88 + j * 16 + lm] = (unsigned short)(pc.u >> 16);
      }
    #pragma unroll
    for (int st = 0; st < 2; ++st) {
      short8 ap = *(const short8*)(Pw + lm * 88 + st * 32 + quad * 8);
      const int kc = ((st * 4 + quad) ^ (lm & 7)) * 8;
      #pragma unroll
      for (int j = 0; j < 4; ++j) {
        short8 vv = *(const short8*)(Vts + (j * 16 + lm) * 64 + kc);
        oacc[j] = __builtin_amdgcn_mfma_f32_16x16x32_bf16(ap, vv, oacc[j], 0, 0, 0);
      }
      oacc[4] = __builtin_amdgcn_mfma_f32_16x16x32_bf16(ap, bones, oacc[4], 0, 0, 0);
    }
  }
  float inv[4];
  #pragma unroll
  for (int r = 0; r < 4; ++r) {
    const float lv = __shfl(oacc[4][r], l & 48, 64);
    inv[r] = 1.f / lv;
  }
  const size_t obase =
      (size_t)b * SS * CC + (size_t)(q0 + w * 16 + quad * 4) * CC + h * 64 + lm;
  #pragma unroll
  for (int j = 0; j < 4; ++j)
    #pragma unroll
    for (int r = 0; r < 4; ++r)
      Oh[obase + (size_t)r * CC + j * 16] = f2bf(oacc[j][r] * inv[r]);
}

extern "C" void kernel_launch(void* const* d_in, const int* in_sizes, int n_in,
                              void* d_out, int out_size, void* d_ws, size_t ws_size,
                              hipStream_t stream) {
  const float* x    = (const float*)d_in[0];
  const float* K_W  = (const float*)d_in[2];
  const float* K_b  = (const float*)d_in[3];
  const float* Q_W  = (const float*)d_in[4];
  const float* Q_b  = (const float*)d_in[5];
  const float* V_W  = (const float*)d_in[6];
  const float* V_b  = (const float*)d_in[7];
  const float* O_W  = (const float*)d_in[8];
  const float* O_b  = (const float*)d_in[9];
  const float* ln1g = (const float*)d_in[10];
  const float* ln1b = (const float*)d_in[11];
  const float* ln2g = (const float*)d_in[12];
  const float* ln2b = (const float*)d_in[13];
  const float* W1   = (const float*)d_in[14];
  const float* b1   = (const float*)d_in[15];
  const float* W2   = (const float*)d_in[16];
  const float* b2   = (const float*)d_in[17];
  float* out = (float*)d_out;

  unsigned char* ws = (unsigned char*)d_ws;
  const size_t MB = 1u << 20;
  unsigned short* qkh   = (unsigned short*)(ws);             // (B,S,1024) 16MB
  unsigned short* qkl   = (unsigned short*)(ws + 16 * MB);   // 16MB
  unsigned short* vt    = (unsigned short*)(ws + 32 * MB);   // (B,NH,HD,S) 8MB
  unsigned short* ln1h  = (unsigned short*)(ws + 40 * MB);   // 8MB
  unsigned short* ln1l  = (unsigned short*)(ws + 48 * MB);   // 8MB
  unsigned short* xsh   = (unsigned short*)(ws + 56 * MB);   // 8MB
  unsigned short* xsl   = (unsigned short*)(ws + 64 * MB);   // 8MB
  unsigned short* oh    = ln1h;
  float* out1           = (float*)(ws + 72 * MB);            // 16MB
  unsigned short* ln2h  = qkh;
  unsigned short* geluh = (unsigned short*)(ws + 8 * MB);
  unsigned short* BtAll = (unsigned short*)(ws + 88 * MB);
  unsigned short* BtQKh = BtAll;
  unsigned short* BtVh  = BtAll + 1024 * 512;
  unsigned short* BtQKl = BtVh + 512 * 512;
  unsigned short* BtOh  = BtQKl + 1024 * 512;
  unsigned short* BtOl  = BtOh + 512 * 512;
  unsigned short* BtW1h = BtOl + 512 * 512;
  unsigned short* BtW2h = BtW1h + 512 * 512;
  float* qkvb           = (float*)(BtW2h + 512 * 512);
  float2* mustd         = (float2*)(ws + 96 * MB);

  dim3 tb32(32, 8);
  convert_and_stats<<<1536 + 128, 256, 0, stream>>>(
      Q_W, K_W, V_W, O_W, W1, W2, Q_b, K_b, V_b,
      BtQKh, BtQKl, BtVh, BtOh, BtOl, BtW1h, BtW2h, qkvb, x, mustd);
  ln1_apply<<<dim3(SS / 32, CC / 32, BB), tb32, 0, stream>>>(
      x, mustd, ln1g, ln1b, ln1h, ln1l, xsh, xsl);
  gemm_qkv<<<768, 256, 0, stream>>>(
      ln1h, ln1l, BtAll, BtQKl, qkvb, qkh, qkl, vt);
  attn_mfma<<<1024, 256, 0, stream>>>(qkh, qkl, vt, oh);
  gemm64<1, 0, 0, 2, 0><<<1024, 256, 0, stream>>>(
      oh, BtOh, BtOl, O_b, nullptr, xsh, xsl, nullptr, out1, CC);
  ln_bf16_k<<<BB * SS, 256, 0, stream>>>(out1, ln2g, ln2b, ln2h);
  gemm64<0, 1, 1, 0, 0><<<1024, 256, 0, stream>>>(
      ln2h, BtW1h, nullptr, b1, nullptr, nullptr, nullptr, geluh, nullptr, CC);
  gemm64<0, 0, 0, 1, 1><<<1024, 256, 0, stream>>>(
      geluh, BtW2h, nullptr, b2, out1, nullptr, nullptr, nullptr, out, CC);
}